// Round 2
// baseline (53985.089 us; speedup 1.0000x reference)
//
#include <hip/hip_runtime.h>
#include <hip/hip_bf16.h>
#include <cstddef>

constexpr int B_ = 8, TT = 1024, H_ = 8, HD_ = 64, D_ = 512, F_ = 2048;
constexpr int L_ = 12, R_ = 1024, NR_ = 2049, C_ = 64, M_ = 128, V_ = 2048;
constexpr int BT_ = B_ * TT;  // 8192

// ---------------------------------------------------------------- embedding + posenc
__global__ void embed_kernel(const int* __restrict__ x, const float* __restrict__ emb,
                             float* __restrict__ h) {
  int bt = blockIdx.x;
  int t = bt & (TT - 1);
  int tok = x[bt];
  const float c = -9.210340371976184f / 512.0f;  // -ln(10000)/D
  size_t base = (size_t)bt * D_;
  size_t ebase = (size_t)tok * D_;
  for (int d = threadIdx.x; d < D_; d += 256) {
    int i = d >> 1;
    float div = expf((float)(2 * i) * c);
    float arg = (float)t * div;
    float pe = (d & 1) ? cosf(arg) : sinf(arg);
    h[base + d] = emb[ebase + d] * 22.627416997969522f + pe;  // sqrt(512)
  }
}

// ---------------------------------------------------------------- generic tiled GEMM: C = A@W + bias (opt ReLU)
// A: (M,K) row-major, W: (K,N) row-major. M%64==0, N%64==0, K%16==0.
template <int RELU>
__global__ __launch_bounds__(256) void gemm_bias(const float* __restrict__ A,
                                                 const float* __restrict__ W,
                                                 const float* __restrict__ bias,
                                                 float* __restrict__ Cm,
                                                 int M, int N, int K) {
  __shared__ float As[64][17];
  __shared__ float Bs[16][65];
  int tid = threadIdx.x;
  int tx = tid & 15, ty = tid >> 4;
  int row0 = blockIdx.y * 64, col0 = blockIdx.x * 64;
  float acc[4][4] = {};
  int ra = tid >> 4, ca = tid & 15;   // A-tile loader coords
  int rb = tid >> 6, cb = tid & 63;   // B-tile loader coords
  for (int k0 = 0; k0 < K; k0 += 16) {
    for (int rr = ra; rr < 64; rr += 16)
      As[rr][ca] = A[(size_t)(row0 + rr) * K + k0 + ca];
    for (int rr = rb; rr < 16; rr += 4)
      Bs[rr][cb] = W[(size_t)(k0 + rr) * N + col0 + cb];
    __syncthreads();
#pragma unroll
    for (int kk = 0; kk < 16; ++kk) {
      float a[4], bb[4];
#pragma unroll
      for (int i = 0; i < 4; ++i) a[i] = As[ty * 4 + i][kk];
#pragma unroll
      for (int j = 0; j < 4; ++j) bb[j] = Bs[kk][tx * 4 + j];
#pragma unroll
      for (int i = 0; i < 4; ++i)
#pragma unroll
        for (int j = 0; j < 4; ++j) acc[i][j] += a[i] * bb[j];
    }
    __syncthreads();
  }
#pragma unroll
  for (int i = 0; i < 4; ++i) {
#pragma unroll
    for (int j = 0; j < 4; ++j) {
      float vv = acc[i][j] + bias[col0 + tx * 4 + j];
      if (RELU) vv = fmaxf(vv, 0.0f);
      Cm[(size_t)(row0 + ty * 4 + i) * N + col0 + tx * 4 + j] = vv;
    }
  }
}

// ---------------------------------------------------------------- fused causal attention, one q-row per block
// q,k,v in (B,T,H,HD) = (BT, D) layout. rel: (NR, HD) for this layer.
// score = (q . (k + rel[k - t + R])) / 8 ; causal ; softmax ; o = p @ v
__global__ __launch_bounds__(256) void attn_kernel(const float* __restrict__ q,
                                                   const float* __restrict__ k,
                                                   const float* __restrict__ v,
                                                   const float* __restrict__ rel,
                                                   float* __restrict__ o) {
  int idx = blockIdx.x;
  int t = idx & (TT - 1);
  int bh = idx >> 10;
  int hh = bh & (H_ - 1);
  int b = bh >> 3;
  int tid = threadIdx.x;

  __shared__ float sq[HD_];
  __shared__ float ss[TT];
  __shared__ float red[256];
  __shared__ float po[4][HD_];

  const float* qrow = q + ((size_t)(b * TT + t)) * D_ + hh * HD_;
  if (tid < HD_) sq[tid] = qrow[tid];
  __syncthreads();

  int nk = t + 1;
  float lmax = -1e30f;
  for (int kk = tid; kk < nk; kk += 256) {
    const float* krow = k + ((size_t)(b * TT + kk)) * D_ + hh * HD_;
    const float* rrow = rel + (size_t)(kk - t + R_) * HD_;
    float s = 0.0f;
#pragma unroll
    for (int d = 0; d < HD_; ++d) s += sq[d] * (krow[d] + rrow[d]);
    s *= 0.125f;
    ss[kk] = s;
    lmax = fmaxf(lmax, s);
  }
  red[tid] = lmax;
  __syncthreads();
  for (int off = 128; off > 0; off >>= 1) {
    if (tid < off) red[tid] = fmaxf(red[tid], red[tid + off]);
    __syncthreads();
  }
  float mx = red[0];
  __syncthreads();

  float lsum = 0.0f;
  for (int kk = tid; kk < nk; kk += 256) {
    float p = expf(ss[kk] - mx);
    ss[kk] = p;
    lsum += p;
  }
  red[tid] = lsum;
  __syncthreads();
  for (int off = 128; off > 0; off >>= 1) {
    if (tid < off) red[tid] += red[tid + off];
    __syncthreads();
  }
  float denom = red[0];
  __syncthreads();

  // o accumulation: (group, d) = (tid/64, tid%64)
  int g = tid >> 6, d = tid & 63;
  float acc = 0.0f;
  for (int kk = g; kk < nk; kk += 4) {
    acc += ss[kk] * v[((size_t)(b * TT + kk)) * D_ + hh * HD_ + d];
  }
  po[g][d] = acc;
  __syncthreads();
  if (tid < HD_) {
    float r = (po[0][tid] + po[1][tid] + po[2][tid] + po[3][tid]) / denom;
    o[((size_t)(b * TT + t)) * D_ + hh * HD_ + tid] = r;
  }
}

// ---------------------------------------------------------------- residual + layernorm (in-place on h)
__global__ __launch_bounds__(256) void ln_res_kernel(float* __restrict__ h,
                                                     const float* __restrict__ y,
                                                     const float* __restrict__ s,
                                                     const float* __restrict__ bvec) {
  int row = blockIdx.x;
  int tid = threadIdx.x;
  size_t base = (size_t)row * D_;
  float z0 = h[base + tid] + y[base + tid];
  float z1 = h[base + tid + 256] + y[base + tid + 256];
  __shared__ float r1[256], r2[256];
  r1[tid] = z0 + z1;
  r2[tid] = z0 * z0 + z1 * z1;
  __syncthreads();
  for (int off = 128; off > 0; off >>= 1) {
    if (tid < off) {
      r1[tid] += r1[tid + off];
      r2[tid] += r2[tid + off];
    }
    __syncthreads();
  }
  float mu = r1[0] * (1.0f / 512.0f);
  float var = r2[0] * (1.0f / 512.0f) - mu * mu;
  float rs = rsqrtf(var + 1e-5f);
  h[base + tid] = (z0 - mu) * rs * s[tid] + bvec[tid];
  h[base + tid + 256] = (z1 - mu) * rs * s[tid + 256] + bvec[tid + 256];
}

// ---------------------------------------------------------------- chord gather
__global__ void gather_kernel(const float* __restrict__ h, const int* __restrict__ pos,
                              float* __restrict__ g) {
  int row = blockIdx.x;  // b*M + m
  int b = row >> 7;      // M=128
  int p = pos[row];
  if (p < 0) p = 0;
  size_t src = ((size_t)(b * TT + p)) * D_;
  size_t dst = (size_t)row * D_;
  for (int d = threadIdx.x; d < D_; d += 256) g[dst + d] = h[src + d];
}

// ---------------------------------------------------------------- launcher
extern "C" void kernel_launch(void* const* d_in, const int* in_sizes, int n_in,
                              void* d_out, int out_size, void* d_ws, size_t ws_size,
                              hipStream_t stream) {
  const int* x = (const int*)d_in[0];
  const int* cpos = (const int*)d_in[1];
  const float* emb = (const float*)d_in[2];
  const float* rel = (const float*)d_in[3];
  const float* Wq = (const float*)d_in[4];
  const float* bq = (const float*)d_in[5];
  const float* Wk = (const float*)d_in[6];
  const float* bk = (const float*)d_in[7];
  const float* Wv = (const float*)d_in[8];
  const float* bv = (const float*)d_in[9];
  const float* Wo = (const float*)d_in[10];
  const float* bo = (const float*)d_in[11];
  const float* ln1s = (const float*)d_in[12];
  const float* ln1b = (const float*)d_in[13];
  const float* W1 = (const float*)d_in[14];
  const float* b1 = (const float*)d_in[15];
  const float* W2 = (const float*)d_in[16];
  const float* b2 = (const float*)d_in[17];
  const float* ln2s = (const float*)d_in[18];
  const float* ln2b = (const float*)d_in[19];
  const float* Wout = (const float*)d_in[20];
  const float* bout = (const float*)d_in[21];
  const float* Wc = (const float*)d_in[22];
  const float* bc = (const float*)d_in[23];

  float* ws = (float*)d_ws;
  const size_t SZ = (size_t)BT_ * D_;  // 4194304
  float* h = ws;
  float* q = ws + SZ;
  float* k = ws + 2 * SZ;
  float* v = ws + 3 * SZ;
  float* o = ws + 4 * SZ;
  float* mid = ws + 5 * SZ;  // BT_*F_ floats
  float* out = (float*)d_out;

  embed_kernel<<<BT_, 256, 0, stream>>>(x, emb, h);

  dim3 gProj(D_ / 64, BT_ / 64);
  dim3 gF1(F_ / 64, BT_ / 64);
  dim3 gOut(V_ / 64, BT_ / 64);

  for (int l = 0; l < L_; ++l) {
    const float* wq = Wq + (size_t)l * D_ * D_;
    const float* wk = Wk + (size_t)l * D_ * D_;
    const float* wv = Wv + (size_t)l * D_ * D_;
    const float* wo = Wo + (size_t)l * D_ * D_;
    gemm_bias<0><<<gProj, 256, 0, stream>>>(h, wq, bq + l * D_, q, BT_, D_, D_);
    gemm_bias<0><<<gProj, 256, 0, stream>>>(h, wk, bk + l * D_, k, BT_, D_, D_);
    gemm_bias<0><<<gProj, 256, 0, stream>>>(h, wv, bv + l * D_, v, BT_, D_, D_);
    attn_kernel<<<B_ * H_ * TT, 256, 0, stream>>>(q, k, v, rel + (size_t)l * NR_ * HD_, o);
    gemm_bias<0><<<gProj, 256, 0, stream>>>(o, wo, bo + l * D_, q, BT_, D_, D_);
    ln_res_kernel<<<BT_, 256, 0, stream>>>(h, q, ln1s + l * D_, ln1b + l * D_);
    gemm_bias<1><<<gF1, 256, 0, stream>>>(h, W1 + (size_t)l * D_ * F_, b1 + l * F_, mid, BT_, F_, D_);
    gemm_bias<0><<<gProj, 256, 0, stream>>>(mid, W2 + (size_t)l * F_ * D_, b2 + l * D_, q, BT_, D_, F_);
    ln_res_kernel<<<BT_, 256, 0, stream>>>(h, q, ln2s + l * D_, ln2b + l * D_);
  }

  gemm_bias<0><<<gOut, 256, 0, stream>>>(h, Wout, bout, out, BT_, V_, D_);
  gather_kernel<<<B_ * M_, 256, 0, stream>>>(h, cpos, q);
  gemm_bias<0><<<dim3(1, (B_ * M_) / 64), 256, 0, stream>>>(q, Wc, bc, out + (size_t)BT_ * V_,
                                                            B_ * M_, C_, D_);
}

// Round 4
// 21208.987 us; speedup vs baseline: 2.5454x; 2.5454x over previous
//
#include <hip/hip_runtime.h>
#include <hip/hip_bf16.h>
#include <cstddef>

constexpr int B_ = 8, TT = 1024, H_ = 8, HD_ = 64, D_ = 512, F_ = 2048;
constexpr int L_ = 12, R_ = 1024, NR_ = 2049, C_ = 64, M_ = 128, V_ = 2048;
constexpr int BT_ = B_ * TT;  // 8192

// XOR swizzle on the d-index (floats, keeps 4-aligned blocks contiguous)
__device__ __forceinline__ int SWZ(int row) { return ((row >> 2) & 7) << 2; }

// ---------------------------------------------------------------- embedding + posenc
__global__ void embed_kernel(const int* __restrict__ x, const float* __restrict__ emb,
                             float* __restrict__ h) {
  int bt = blockIdx.x;
  int t = bt & (TT - 1);
  int tok = x[bt];
  const float c = -9.210340371976184f / 512.0f;  // -ln(10000)/D
  size_t base = (size_t)bt * D_;
  size_t ebase = (size_t)tok * D_;
  for (int d = threadIdx.x; d < D_; d += 256) {
    int i = d >> 1;
    float div = expf((float)(2 * i) * c);
    float arg = (float)t * div;
    float pe = (d & 1) ? cosf(arg) : sinf(arg);
    h[base + d] = emb[ebase + d] * 22.627416997969522f + pe;  // sqrt(512)
  }
}

// ---------------------------------------------------------------- generic tiled GEMM: C = A@W + bias (opt ReLU)
template <int RELU>
__global__ __launch_bounds__(256) void gemm_bias(const float* __restrict__ A,
                                                 const float* __restrict__ W,
                                                 const float* __restrict__ bias,
                                                 float* __restrict__ Cm,
                                                 int M, int N, int K) {
  __shared__ float As[64][17];
  __shared__ float Bs[16][65];
  int tid = threadIdx.x;
  int tx = tid & 15, ty = tid >> 4;
  int row0 = blockIdx.y * 64, col0 = blockIdx.x * 64;
  float acc[4][4] = {};
  int ra = tid >> 4, ca = tid & 15;
  int rb = tid >> 6, cb = tid & 63;
  for (int k0 = 0; k0 < K; k0 += 16) {
    for (int rr = ra; rr < 64; rr += 16)
      As[rr][ca] = A[(size_t)(row0 + rr) * K + k0 + ca];
    for (int rr = rb; rr < 16; rr += 4)
      Bs[rr][cb] = W[(size_t)(k0 + rr) * N + col0 + cb];
    __syncthreads();
#pragma unroll
    for (int kk = 0; kk < 16; ++kk) {
      float a[4], bb[4];
#pragma unroll
      for (int i = 0; i < 4; ++i) a[i] = As[ty * 4 + i][kk];
#pragma unroll
      for (int j = 0; j < 4; ++j) bb[j] = Bs[kk][tx * 4 + j];
#pragma unroll
      for (int i = 0; i < 4; ++i)
#pragma unroll
        for (int j = 0; j < 4; ++j) acc[i][j] += a[i] * bb[j];
    }
    __syncthreads();
  }
#pragma unroll
  for (int i = 0; i < 4; ++i) {
#pragma unroll
    for (int j = 0; j < 4; ++j) {
      float vv = acc[i][j] + bias[col0 + tx * 4 + j];
      if (RELU) vv = fmaxf(vv, 0.0f);
      Cm[(size_t)(row0 + ty * 4 + i) * N + col0 + tx * 4 + j] = vv;
    }
  }
}

// ---------------------------------------------------------------- tiled causal attention with fused rel-pos
// Per block: 64 q-rows of one (b,h); loop over 32-wide k-tiles.
// S[r][c] = (q[r] . (k[c] + rel[c-r+R])) / 8 ; online softmax ; O += P@V
// Thread (tx,ty): S cols 2tx+j (k-axis), O cols 4tx+j (d-axis), rows 4ty+i.
__global__ __launch_bounds__(256) void attn_tiled(const float* __restrict__ q,
                                                  const float* __restrict__ k,
                                                  const float* __restrict__ v,
                                                  const float* __restrict__ rel,
                                                  float* __restrict__ o) {
  __shared__ float Qs[64][64];   // 16 KB (swizzled)
  __shared__ float Ks[32][64];   // 8 KB
  __shared__ float Vs[32][64];   // 8 KB
  __shared__ float Ps[32][64];   // 8 KB  Ps[kk][r] = P[r][kk]
  __shared__ float Rs[95][64];   // 23.75 KB  Rs[rr] = rel row (k0-t0+961+rr)

  int blk = blockIdx.x;
  int qt = blk & 15;
  int bh = blk >> 4;
  int hh = bh & 7;
  int b = bh >> 3;
  int t0 = qt << 6;
  int tid = threadIdx.x;
  int tx = tid & 15, ty = tid >> 4;

  const float* qg = q + ((size_t)(b * TT + t0)) * D_ + hh * HD_;
  const float* kg = k + ((size_t)b * TT) * D_ + hh * HD_;
  const float* vg = v + ((size_t)b * TT) * D_ + hh * HD_;

  // stage Q, pre-scaled by 1/8
  {
    int row = tid >> 2, seg = (tid & 3) << 4;
    const float* src = qg + (size_t)row * D_ + seg;
    int sw = SWZ(row);
#pragma unroll
    for (int s4 = 0; s4 < 4; ++s4) {
      float4 val = *(const float4*)(src + s4 * 4);
      val.x *= 0.125f; val.y *= 0.125f; val.z *= 0.125f; val.w *= 0.125f;
      *(float4*)&Qs[row][(seg + s4 * 4) ^ sw] = val;
    }
  }

  float Oa[4][4] = {};
  float mrow[4] = {-1e30f, -1e30f, -1e30f, -1e30f};
  float lrow[4] = {};

  int nkt = (t0 >> 5) + 2;
  for (int kt = 0; kt < nkt; ++kt) {
    int k0 = kt << 5;
    __syncthreads();  // prior PV done before restage
    {
      int row = tid >> 3, seg = (tid & 7) << 3;
      const float* ksrc = kg + (size_t)(k0 + row) * D_ + seg;
      const float* vsrc = vg + (size_t)(k0 + row) * D_ + seg;
      int sw = SWZ(row);
#pragma unroll
      for (int s4 = 0; s4 < 2; ++s4) {
        *(float4*)&Ks[row][(seg + s4 * 4) ^ sw] = *(const float4*)(ksrc + s4 * 4);
        *(float4*)&Vs[row][(seg + s4 * 4) ^ sw] = *(const float4*)(vsrc + s4 * 4);
      }
      const float* rbase = rel + (size_t)(k0 - t0 + 961) * HD_;  // 961 = R - 63
      for (int rr = tid >> 3; rr < 95; rr += 32) {
        int swr = SWZ(rr);
        const float* rsrc = rbase + (size_t)rr * HD_ + seg;
#pragma unroll
        for (int s4 = 0; s4 < 2; ++s4)
          *(float4*)&Rs[rr][(seg + s4 * 4) ^ swr] = *(const float4*)(rsrc + s4 * 4);
      }
    }
    __syncthreads();

    // S tile: rows 4ty+i, cols 2tx+j
    float acc[4][2] = {};
    int rb = 2 * tx - 4 * ty + 63;  // Rs row for (i=0,j=0)
    {
      int swq = (ty & 7) << 2;
#pragma unroll
      for (int d0 = 0; d0 < 64; d0 += 4) {
        float4 qv[4], kv[2], rv[5];
#pragma unroll
        for (int i = 0; i < 4; ++i) qv[i] = *(const float4*)&Qs[4 * ty + i][d0 ^ swq];
#pragma unroll
        for (int j = 0; j < 2; ++j) kv[j] = *(const float4*)&Ks[2 * tx + j][d0 ^ SWZ(2 * tx + j)];
#pragma unroll
        for (int u = 0; u < 5; ++u) {
          int rr = rb + u - 3;
          rv[u] = *(const float4*)&Rs[rr][d0 ^ SWZ(rr)];
        }
#pragma unroll
        for (int dd = 0; dd < 4; ++dd) {
#pragma unroll
          for (int i = 0; i < 4; ++i) {
            float qq = ((const float*)&qv[i])[dd];
#pragma unroll
            for (int j = 0; j < 2; ++j) {
              acc[i][j] += qq * ((const float*)&kv[j])[dd];
              acc[i][j] += qq * ((const float*)&rv[j - i + 3])[dd];
            }
          }
        }
      }
    }

    // causal mask
#pragma unroll
    for (int i = 0; i < 4; ++i)
#pragma unroll
      for (int j = 0; j < 2; ++j)
        if (k0 + 2 * tx + j > t0 + 4 * ty + i) acc[i][j] = -1e30f;

    // online softmax (rows replicated across the 16-lane tx group)
#pragma unroll
    for (int i = 0; i < 4; ++i) {
      float mx = fmaxf(acc[i][0], acc[i][1]);
      mx = fmaxf(mx, __shfl_xor(mx, 1));
      mx = fmaxf(mx, __shfl_xor(mx, 2));
      mx = fmaxf(mx, __shfl_xor(mx, 4));
      mx = fmaxf(mx, __shfl_xor(mx, 8));
      float mnew = fmaxf(mrow[i], mx);
      float scale = __expf(mrow[i] - mnew);
      mrow[i] = mnew;
      float p0 = __expf(acc[i][0] - mnew);
      float p1 = __expf(acc[i][1] - mnew);
      acc[i][0] = p0; acc[i][1] = p1;
      float ls = p0 + p1;
      ls += __shfl_xor(ls, 1);
      ls += __shfl_xor(ls, 2);
      ls += __shfl_xor(ls, 4);
      ls += __shfl_xor(ls, 8);
      lrow[i] = lrow[i] * scale + ls;
#pragma unroll
      for (int j = 0; j < 4; ++j) Oa[i][j] *= scale;
    }

    // write P transposed: Ps[kk][r]
#pragma unroll
    for (int j = 0; j < 2; ++j) {
      float4 pw = make_float4(acc[0][j], acc[1][j], acc[2][j], acc[3][j]);
      *(float4*)&Ps[2 * tx + j][(4 * ty) ^ SWZ(2 * tx + j)] = pw;
    }
    __syncthreads();

    // PV: O[4ty+i][4tx+j] += sum_kk P[4ty+i][kk] * V[kk][4tx+j]
#pragma unroll 8
    for (int kk = 0; kk < 32; ++kk) {
      int sw = SWZ(kk);
      float4 pv = *(const float4*)&Ps[kk][(4 * ty) ^ sw];
      float4 vv = *(const float4*)&Vs[kk][(4 * tx) ^ sw];
      const float* pf = (const float*)&pv;
      const float* vf = (const float*)&vv;
#pragma unroll
      for (int i = 0; i < 4; ++i)
#pragma unroll
        for (int j = 0; j < 4; ++j) Oa[i][j] += pf[i] * vf[j];
    }
  }

  float* og = o + ((size_t)(b * TT + t0)) * D_ + hh * HD_;
#pragma unroll
  for (int i = 0; i < 4; ++i) {
    float inv = 1.0f / lrow[i];
#pragma unroll
    for (int j = 0; j < 4; ++j)
      og[(size_t)(4 * ty + i) * D_ + 4 * tx + j] = Oa[i][j] * inv;
  }
}

// ---------------------------------------------------------------- residual + layernorm (in-place on h)
__global__ __launch_bounds__(256) void ln_res_kernel(float* __restrict__ h,
                                                     const float* __restrict__ y,
                                                     const float* __restrict__ s,
                                                     const float* __restrict__ bvec) {
  int row = blockIdx.x;
  int tid = threadIdx.x;
  size_t base = (size_t)row * D_;
  float z0 = h[base + tid] + y[base + tid];
  float z1 = h[base + tid + 256] + y[base + tid + 256];
  __shared__ float r1[256], r2[256];
  r1[tid] = z0 + z1;
  r2[tid] = z0 * z0 + z1 * z1;
  __syncthreads();
  for (int off = 128; off > 0; off >>= 1) {
    if (tid < off) {
      r1[tid] += r1[tid + off];
      r2[tid] += r2[tid + off];
    }
    __syncthreads();
  }
  float mu = r1[0] * (1.0f / 512.0f);
  float var = r2[0] * (1.0f / 512.0f) - mu * mu;
  float rs = rsqrtf(var + 1e-5f);
  h[base + tid] = (z0 - mu) * rs * s[tid] + bvec[tid];
  h[base + tid + 256] = (z1 - mu) * rs * s[tid + 256] + bvec[tid + 256];
}

// ---------------------------------------------------------------- chord gather
__global__ void gather_kernel(const float* __restrict__ h, const int* __restrict__ pos,
                              float* __restrict__ g) {
  int row = blockIdx.x;
  int b = row >> 7;
  int p = pos[row];
  if (p < 0) p = 0;
  size_t src = ((size_t)(b * TT + p)) * D_;
  size_t dst = (size_t)row * D_;
  for (int d = threadIdx.x; d < D_; d += 256) g[dst + d] = h[src + d];
}

// ---------------------------------------------------------------- launcher
extern "C" void kernel_launch(void* const* d_in, const int* in_sizes, int n_in,
                              void* d_out, int out_size, void* d_ws, size_t ws_size,
                              hipStream_t stream) {
  const int* x = (const int*)d_in[0];
  const int* cpos = (const int*)d_in[1];
  const float* emb = (const float*)d_in[2];
  const float* rel = (const float*)d_in[3];
  const float* Wq = (const float*)d_in[4];
  const float* bq = (const float*)d_in[5];
  const float* Wk = (const float*)d_in[6];
  const float* bk = (const float*)d_in[7];
  const float* Wv = (const float*)d_in[8];
  const float* bv = (const float*)d_in[9];
  const float* Wo = (const float*)d_in[10];
  const float* bo = (const float*)d_in[11];
  const float* ln1s = (const float*)d_in[12];
  const float* ln1b = (const float*)d_in[13];
  const float* W1 = (const float*)d_in[14];
  const float* b1 = (const float*)d_in[15];
  const float* W2 = (const float*)d_in[16];
  const float* b2 = (const float*)d_in[17];
  const float* ln2s = (const float*)d_in[18];
  const float* ln2b = (const float*)d_in[19];
  const float* Wout = (const float*)d_in[20];
  const float* bout = (const float*)d_in[21];
  const float* Wc = (const float*)d_in[22];
  const float* bc = (const float*)d_in[23];

  float* ws = (float*)d_ws;
  const size_t SZ = (size_t)BT_ * D_;
  float* h = ws;
  float* q = ws + SZ;
  float* k = ws + 2 * SZ;
  float* v = ws + 3 * SZ;
  float* o = ws + 4 * SZ;
  float* mid = ws + 5 * SZ;
  float* out = (float*)d_out;

  embed_kernel<<<BT_, 256, 0, stream>>>(x, emb, h);

  dim3 gProj(D_ / 64, BT_ / 64);
  dim3 gF1(F_ / 64, BT_ / 64);
  dim3 gOut(V_ / 64, BT_ / 64);

  for (int l = 0; l < L_; ++l) {
    const float* wq = Wq + (size_t)l * D_ * D_;
    const float* wk = Wk + (size_t)l * D_ * D_;
    const float* wv = Wv + (size_t)l * D_ * D_;
    const float* wo = Wo + (size_t)l * D_ * D_;
    gemm_bias<0><<<gProj, 256, 0, stream>>>(h, wq, bq + l * D_, q, BT_, D_, D_);
    gemm_bias<0><<<gProj, 256, 0, stream>>>(h, wk, bk + l * D_, k, BT_, D_, D_);
    gemm_bias<0><<<gProj, 256, 0, stream>>>(h, wv, bv + l * D_, v, BT_, D_, D_);
    attn_tiled<<<B_ * H_ * (TT / 64), 256, 0, stream>>>(q, k, v, rel + (size_t)l * NR_ * HD_, o);
    gemm_bias<0><<<gProj, 256, 0, stream>>>(o, wo, bo + l * D_, q, BT_, D_, D_);
    ln_res_kernel<<<BT_, 256, 0, stream>>>(h, q, ln1s + l * D_, ln1b + l * D_);
    gemm_bias<1><<<gF1, 256, 0, stream>>>(h, W1 + (size_t)l * D_ * F_, b1 + l * F_, mid, BT_, F_, D_);
    gemm_bias<0><<<gProj, 256, 0, stream>>>(mid, W2 + (size_t)l * F_ * D_, b2 + l * D_, q, BT_, D_, F_);
    ln_res_kernel<<<BT_, 256, 0, stream>>>(h, q, ln2s + l * D_, ln2b + l * D_);
  }

  gemm_bias<0><<<gOut, 256, 0, stream>>>(h, Wout, bout, out, BT_, V_, D_);
  gather_kernel<<<B_ * M_, 256, 0, stream>>>(h, cpos, q);
  gemm_bias<0><<<dim3(1, (B_ * M_) / 64), 256, 0, stream>>>(q, Wc, bc, out + (size_t)BT_ * V_,
                                                            B_ * M_, C_, D_);
}

// Round 5
// 7879.766 us; speedup vs baseline: 6.8511x; 2.6916x over previous
//
#include <hip/hip_runtime.h>
#include <hip/hip_bf16.h>
#include <cstddef>

constexpr int B_ = 8, TT = 1024, H_ = 8, HD_ = 64, D_ = 512, F_ = 2048;
constexpr int L_ = 12, R_ = 1024, NR_ = 2049, C_ = 64, M_ = 128, V_ = 2048;
constexpr int BT_ = B_ * TT;  // 8192

typedef short bf16x8_t __attribute__((ext_vector_type(8)));
typedef float f32x4_t __attribute__((ext_vector_type(4)));
typedef unsigned short ushort_t;

__device__ __forceinline__ float b2f(unsigned int u16) {
  return __uint_as_float(u16 << 16);
}
__device__ __forceinline__ ushort_t f2b(float f) {
  __hip_bfloat16 h = __float2bfloat16(f);
  return *reinterpret_cast<ushort_t*>(&h);
}
// attn LDS swizzle (f32 4-elem granule)
__device__ __forceinline__ int SWZ(int row) { return ((row >> 2) & 7) << 2; }

// ---------------------------------------------------------------- weight transpose+convert: src (K,N) f32 -> dst (N,K) bf16
__global__ __launch_bounds__(256) void transpose_bf16(const float* __restrict__ src,
                                                      ushort_t* __restrict__ dst,
                                                      int K, int N) {
  __shared__ float t[32][33];
  int k0 = blockIdx.y * 32, n0 = blockIdx.x * 32;
  int r = threadIdx.x >> 3, c4 = (threadIdx.x & 7) * 4;
  float4 vv = *(const float4*)(src + (size_t)(k0 + r) * N + n0 + c4);
  t[r][c4] = vv.x; t[r][c4 + 1] = vv.y; t[r][c4 + 2] = vv.z; t[r][c4 + 3] = vv.w;
  __syncthreads();
  ushort4 w;
  w.x = f2b(t[c4 + 0][r]); w.y = f2b(t[c4 + 1][r]);
  w.z = f2b(t[c4 + 2][r]); w.w = f2b(t[c4 + 3][r]);
  *(ushort4*)(dst + (size_t)(n0 + r) * K + k0 + c4) = w;
}

// ---------------------------------------------------------------- embedding + posenc (f32 + bf16 out)
__global__ void embed_kernel(const int* __restrict__ x, const float* __restrict__ emb,
                             float* __restrict__ h, ushort_t* __restrict__ h_bf) {
  int bt = blockIdx.x;
  int t = bt & (TT - 1);
  int tok = x[bt];
  const float c = -9.210340371976184f / 512.0f;
  size_t base = (size_t)bt * D_;
  size_t ebase = (size_t)tok * D_;
  for (int d = threadIdx.x; d < D_; d += 256) {
    int i = d >> 1;
    float div = expf((float)(2 * i) * c);
    float arg = (float)t * div;
    float pe = (d & 1) ? cosf(arg) : sinf(arg);
    float vv = emb[ebase + d] * 22.627416997969522f + pe;
    h[base + d] = vv;
    h_bf[base + d] = f2b(vv);
  }
}

// ---------------------------------------------------------------- MFMA GEMM: C = A@B + bias
// A: (M,K) bf16 row-major. BT: (N,K) bf16 row-major (B transposed). bias f32.
// 128x128 tile, BK=32, 4 waves (2x2), 16x mfma_f32_16x16x32_bf16 per wave/K-step.
template <int OUT_BF16, int RELU>
__global__ __launch_bounds__(256) void gemm_mfma(const ushort_t* __restrict__ A,
                                                 const ushort_t* __restrict__ Bt,
                                                 const float* __restrict__ bias,
                                                 void* __restrict__ Cout,
                                                 int Mm, int N, int K) {
  __shared__ ushort_t As[128 * 32];
  __shared__ ushort_t Bs[128 * 32];
  int tid = threadIdx.x;
  int m0 = blockIdx.y * 128, n0 = blockIdx.x * 128;
  int lane = tid & 63, wid = tid >> 6;
  int wr = wid >> 1, wc = wid & 1;

  f32x4_t acc[4][4];
#pragma unroll
  for (int mi = 0; mi < 4; ++mi)
#pragma unroll
    for (int ni = 0; ni < 4; ++ni) acc[mi][ni] = (f32x4_t){0.f, 0.f, 0.f, 0.f};

  // staging: 512 chunks of 16B per tile; thread handles chunks tid and tid+256.
  // chunk c -> row c>>2, LDS granule pos p=c&3, source k-granule kg = p ^ ((row>>1)&3)
  int c0 = tid, c1 = tid + 256;
  int ar0 = c0 >> 2, ap0 = c0 & 3, akg0 = ap0 ^ ((ar0 >> 1) & 3);
  int ar1 = c1 >> 2, ap1 = c1 & 3, akg1 = ap1 ^ ((ar1 >> 1) & 3);
  const ushort_t* Arow0 = A + (size_t)(m0 + ar0) * K + akg0 * 8;
  const ushort_t* Arow1 = A + (size_t)(m0 + ar1) * K + akg1 * 8;
  const ushort_t* Brow0 = Bt + (size_t)(n0 + ar0) * K + akg0 * 8;
  const ushort_t* Brow1 = Bt + (size_t)(n0 + ar1) * K + akg1 * 8;

  uint4 ra0 = *(const uint4*)(Arow0);
  uint4 ra1 = *(const uint4*)(Arow1);
  uint4 rb0 = *(const uint4*)(Brow0);
  uint4 rb1 = *(const uint4*)(Brow1);

  int NT = K >> 5;
  int kg = lane >> 4, rl = lane & 15;
  for (int kt = 0; kt < NT; ++kt) {
    __syncthreads();
    *(uint4*)&As[ar0 * 32 + ap0 * 8] = ra0;
    *(uint4*)&As[ar1 * 32 + ap1 * 8] = ra1;
    *(uint4*)&Bs[ar0 * 32 + ap0 * 8] = rb0;
    *(uint4*)&Bs[ar1 * 32 + ap1 * 8] = rb1;
    __syncthreads();
    if (kt + 1 < NT) {
      int ko = (kt + 1) << 5;
      ra0 = *(const uint4*)(Arow0 + ko);
      ra1 = *(const uint4*)(Arow1 + ko);
      rb0 = *(const uint4*)(Brow0 + ko);
      rb1 = *(const uint4*)(Brow1 + ko);
    }
    bf16x8_t fa[4], fb[4];
#pragma unroll
    for (int mi = 0; mi < 4; ++mi) {
      int r = wr * 64 + mi * 16 + rl;
      fa[mi] = *(bf16x8_t*)&As[r * 32 + ((kg ^ ((r >> 1) & 3)) << 3)];
    }
#pragma unroll
    for (int ni = 0; ni < 4; ++ni) {
      int r = wc * 64 + ni * 16 + rl;
      fb[ni] = *(bf16x8_t*)&Bs[r * 32 + ((kg ^ ((r >> 1) & 3)) << 3)];
    }
#pragma unroll
    for (int mi = 0; mi < 4; ++mi)
#pragma unroll
      for (int ni = 0; ni < 4; ++ni)
        acc[mi][ni] = __builtin_amdgcn_mfma_f32_16x16x32_bf16(fa[mi], fb[ni], acc[mi][ni], 0, 0, 0);
  }

  // epilogue: C/D layout col=lane&15, row=(lane>>4)*4+reg
  int rg = lane >> 4;
#pragma unroll
  for (int ni = 0; ni < 4; ++ni) {
    int col = n0 + wc * 64 + ni * 16 + rl;
    float bv = bias[col];
#pragma unroll
    for (int mi = 0; mi < 4; ++mi) {
      int row0 = m0 + wr * 64 + mi * 16 + rg * 4;
#pragma unroll
      for (int r = 0; r < 4; ++r) {
        float vv = acc[mi][ni][r] + bv;
        if (RELU) vv = fmaxf(vv, 0.0f);
        if (OUT_BF16)
          ((ushort_t*)Cout)[(size_t)(row0 + r) * N + col] = f2b(vv);
        else
          ((float*)Cout)[(size_t)(row0 + r) * N + col] = vv;
      }
    }
  }
}

// ---------------------------------------------------------------- legacy f32 GEMM (chord head only)
template <int RELU>
__global__ __launch_bounds__(256) void gemm_bias(const float* __restrict__ A,
                                                 const float* __restrict__ W,
                                                 const float* __restrict__ bias,
                                                 float* __restrict__ Cm,
                                                 int Mm, int N, int K) {
  __shared__ float As[64][17];
  __shared__ float Bs[16][65];
  int tid = threadIdx.x;
  int tx = tid & 15, ty = tid >> 4;
  int row0 = blockIdx.y * 64, col0 = blockIdx.x * 64;
  float acc[4][4] = {};
  int ra = tid >> 4, ca = tid & 15;
  int rb = tid >> 6, cb = tid & 63;
  for (int k0 = 0; k0 < K; k0 += 16) {
    for (int rr = ra; rr < 64; rr += 16)
      As[rr][ca] = A[(size_t)(row0 + rr) * K + k0 + ca];
    for (int rr = rb; rr < 16; rr += 4)
      Bs[rr][cb] = W[(size_t)(k0 + rr) * N + col0 + cb];
    __syncthreads();
#pragma unroll
    for (int kk = 0; kk < 16; ++kk) {
      float a[4], bb[4];
#pragma unroll
      for (int i = 0; i < 4; ++i) a[i] = As[ty * 4 + i][kk];
#pragma unroll
      for (int j = 0; j < 4; ++j) bb[j] = Bs[kk][tx * 4 + j];
#pragma unroll
      for (int i = 0; i < 4; ++i)
#pragma unroll
        for (int j = 0; j < 4; ++j) acc[i][j] += a[i] * bb[j];
    }
    __syncthreads();
  }
#pragma unroll
  for (int i = 0; i < 4; ++i) {
#pragma unroll
    for (int j = 0; j < 4; ++j) {
      float vv = acc[i][j] + bias[col0 + tx * 4 + j];
      if (RELU) vv = fmaxf(vv, 0.0f);
      Cm[(size_t)(row0 + ty * 4 + i) * N + col0 + tx * 4 + j] = vv;
    }
  }
}

// ---------------------------------------------------------------- tiled causal attention (bf16 q/k/v in, bf16 o out)
__global__ __launch_bounds__(256) void attn_tiled(const ushort_t* __restrict__ q,
                                                  const ushort_t* __restrict__ k,
                                                  const ushort_t* __restrict__ v,
                                                  const float* __restrict__ rel,
                                                  ushort_t* __restrict__ o) {
  __shared__ float Qs[64][64];
  __shared__ float Ks[32][64];
  __shared__ float Vs[32][64];
  __shared__ float Ps[32][64];
  __shared__ float Rs[95][64];

  int blk = blockIdx.x;
  int qt = blk & 15;
  int bh = blk >> 4;
  int hh = bh & 7;
  int b = bh >> 3;
  int t0 = qt << 6;
  int tid = threadIdx.x;
  int tx = tid & 15, ty = tid >> 4;

  const ushort_t* qg = q + ((size_t)(b * TT + t0)) * D_ + hh * HD_;
  const ushort_t* kgp = k + ((size_t)b * TT) * D_ + hh * HD_;
  const ushort_t* vgp = v + ((size_t)b * TT) * D_ + hh * HD_;

  // stage Q (pre-scaled 1/8)
  {
    int row = tid >> 2, s16 = (tid & 3) << 4;
    const ushort_t* src = qg + (size_t)row * D_ + s16;
    int sw = SWZ(row);
#pragma unroll
    for (int hhalf = 0; hhalf < 2; ++hhalf) {
      uint4 u = *(const uint4*)(src + hhalf * 8);
      unsigned int uw[4] = {u.x, u.y, u.z, u.w};
      float f[8];
#pragma unroll
      for (int jj = 0; jj < 4; ++jj) {
        f[2 * jj] = b2f(uw[jj] & 0xffffu) * 0.125f;
        f[2 * jj + 1] = b2f(uw[jj] >> 16) * 0.125f;
      }
#pragma unroll
      for (int g4 = 0; g4 < 2; ++g4) {
        float4 w4 = make_float4(f[g4 * 4], f[g4 * 4 + 1], f[g4 * 4 + 2], f[g4 * 4 + 3]);
        *(float4*)&Qs[row][(s16 + hhalf * 8 + g4 * 4) ^ sw] = w4;
      }
    }
  }

  float Oa[4][4] = {};
  float mrow[4] = {-1e30f, -1e30f, -1e30f, -1e30f};
  float lrow[4] = {};

  int nkt = (t0 >> 5) + 2;
  for (int kt = 0; kt < nkt; ++kt) {
    int k0 = kt << 5;
    __syncthreads();
    {
      int row = tid >> 3, s8 = (tid & 7) << 3;
      int sw = SWZ(row);
      uint4 uk = *(const uint4*)(kgp + (size_t)(k0 + row) * D_ + s8);
      uint4 uv = *(const uint4*)(vgp + (size_t)(k0 + row) * D_ + s8);
      unsigned int kw[4] = {uk.x, uk.y, uk.z, uk.w};
      unsigned int vw[4] = {uv.x, uv.y, uv.z, uv.w};
      float fk[8], fv[8];
#pragma unroll
      for (int jj = 0; jj < 4; ++jj) {
        fk[2 * jj] = b2f(kw[jj] & 0xffffu); fk[2 * jj + 1] = b2f(kw[jj] >> 16);
        fv[2 * jj] = b2f(vw[jj] & 0xffffu); fv[2 * jj + 1] = b2f(vw[jj] >> 16);
      }
#pragma unroll
      for (int g4 = 0; g4 < 2; ++g4) {
        *(float4*)&Ks[row][(s8 + g4 * 4) ^ sw] =
            make_float4(fk[g4 * 4], fk[g4 * 4 + 1], fk[g4 * 4 + 2], fk[g4 * 4 + 3]);
        *(float4*)&Vs[row][(s8 + g4 * 4) ^ sw] =
            make_float4(fv[g4 * 4], fv[g4 * 4 + 1], fv[g4 * 4 + 2], fv[g4 * 4 + 3]);
      }
      const float* rbase = rel + (size_t)(k0 - t0 + 961) * HD_;  // 961 = R - 63
      for (int rr = tid >> 3; rr < 95; rr += 32) {
        int swr = SWZ(rr);
        const float* rsrc = rbase + (size_t)rr * HD_ + s8;
#pragma unroll
        for (int s4 = 0; s4 < 2; ++s4)
          *(float4*)&Rs[rr][(s8 + s4 * 4) ^ swr] = *(const float4*)(rsrc + s4 * 4);
      }
    }
    __syncthreads();

    float acc[4][2] = {};
    int rb = 2 * tx - 4 * ty + 63;
    {
      int swq = (ty & 7) << 2;
#pragma unroll
      for (int d0 = 0; d0 < 64; d0 += 4) {
        float4 qv[4], kv[2], rv[5];
#pragma unroll
        for (int i = 0; i < 4; ++i) qv[i] = *(const float4*)&Qs[4 * ty + i][d0 ^ swq];
#pragma unroll
        for (int j = 0; j < 2; ++j) kv[j] = *(const float4*)&Ks[2 * tx + j][d0 ^ SWZ(2 * tx + j)];
#pragma unroll
        for (int u = 0; u < 5; ++u) {
          int rr = rb + u - 3;
          rv[u] = *(const float4*)&Rs[rr][d0 ^ SWZ(rr)];
        }
#pragma unroll
        for (int dd = 0; dd < 4; ++dd) {
#pragma unroll
          for (int i = 0; i < 4; ++i) {
            float qq = ((const float*)&qv[i])[dd];
#pragma unroll
            for (int j = 0; j < 2; ++j) {
              acc[i][j] += qq * ((const float*)&kv[j])[dd];
              acc[i][j] += qq * ((const float*)&rv[j - i + 3])[dd];
            }
          }
        }
      }
    }

#pragma unroll
    for (int i = 0; i < 4; ++i)
#pragma unroll
      for (int j = 0; j < 2; ++j)
        if (k0 + 2 * tx + j > t0 + 4 * ty + i) acc[i][j] = -1e30f;

#pragma unroll
    for (int i = 0; i < 4; ++i) {
      float mx = fmaxf(acc[i][0], acc[i][1]);
      mx = fmaxf(mx, __shfl_xor(mx, 1));
      mx = fmaxf(mx, __shfl_xor(mx, 2));
      mx = fmaxf(mx, __shfl_xor(mx, 4));
      mx = fmaxf(mx, __shfl_xor(mx, 8));
      float mnew = fmaxf(mrow[i], mx);
      float scale = __expf(mrow[i] - mnew);
      mrow[i] = mnew;
      float p0 = __expf(acc[i][0] - mnew);
      float p1 = __expf(acc[i][1] - mnew);
      acc[i][0] = p0; acc[i][1] = p1;
      float ls = p0 + p1;
      ls += __shfl_xor(ls, 1);
      ls += __shfl_xor(ls, 2);
      ls += __shfl_xor(ls, 4);
      ls += __shfl_xor(ls, 8);
      lrow[i] = lrow[i] * scale + ls;
#pragma unroll
      for (int j = 0; j < 4; ++j) Oa[i][j] *= scale;
    }

#pragma unroll
    for (int j = 0; j < 2; ++j) {
      float4 pw = make_float4(acc[0][j], acc[1][j], acc[2][j], acc[3][j]);
      *(float4*)&Ps[2 * tx + j][(4 * ty) ^ SWZ(2 * tx + j)] = pw;
    }
    __syncthreads();

#pragma unroll 8
    for (int kk = 0; kk < 32; ++kk) {
      int sw = SWZ(kk);
      float4 pv = *(const float4*)&Ps[kk][(4 * ty) ^ sw];
      float4 vv = *(const float4*)&Vs[kk][(4 * tx) ^ sw];
      const float* pf = (const float*)&pv;
      const float* vf = (const float*)&vv;
#pragma unroll
      for (int i = 0; i < 4; ++i)
#pragma unroll
        for (int j = 0; j < 4; ++j) Oa[i][j] += pf[i] * vf[j];
    }
  }

  ushort_t* og = o + ((size_t)(b * TT + t0)) * D_ + hh * HD_;
#pragma unroll
  for (int i = 0; i < 4; ++i) {
    float inv = 1.0f / lrow[i];
    ushort4 w;
    w.x = f2b(Oa[i][0] * inv); w.y = f2b(Oa[i][1] * inv);
    w.z = f2b(Oa[i][2] * inv); w.w = f2b(Oa[i][3] * inv);
    *(ushort4*)(og + (size_t)(4 * ty + i) * D_ + 4 * tx) = w;
  }
}

// ---------------------------------------------------------------- residual + layernorm (f32 h in-place, bf16 copy)
__global__ __launch_bounds__(256) void ln_res_kernel(float* __restrict__ h,
                                                     const float* __restrict__ y,
                                                     const float* __restrict__ s,
                                                     const float* __restrict__ bvec,
                                                     ushort_t* __restrict__ h_bf) {
  int row = blockIdx.x;
  int tid = threadIdx.x;
  size_t base = (size_t)row * D_;
  float z0 = h[base + tid] + y[base + tid];
  float z1 = h[base + tid + 256] + y[base + tid + 256];
  __shared__ float r1[256], r2[256];
  r1[tid] = z0 + z1;
  r2[tid] = z0 * z0 + z1 * z1;
  __syncthreads();
  for (int off = 128; off > 0; off >>= 1) {
    if (tid < off) {
      r1[tid] += r1[tid + off];
      r2[tid] += r2[tid + off];
    }
    __syncthreads();
  }
  float mu = r1[0] * (1.0f / 512.0f);
  float var = r2[0] * (1.0f / 512.0f) - mu * mu;
  float rs = rsqrtf(var + 1e-5f);
  float o0 = (z0 - mu) * rs * s[tid] + bvec[tid];
  float o1 = (z1 - mu) * rs * s[tid + 256] + bvec[tid + 256];
  h[base + tid] = o0;
  h[base + tid + 256] = o1;
  h_bf[base + tid] = f2b(o0);
  h_bf[base + tid + 256] = f2b(o1);
}

// ---------------------------------------------------------------- chord gather (f32)
__global__ void gather_kernel(const float* __restrict__ h, const int* __restrict__ pos,
                              float* __restrict__ g) {
  int row = blockIdx.x;
  int b = row >> 7;
  int p = pos[row];
  if (p < 0) p = 0;
  size_t src = ((size_t)(b * TT + p)) * D_;
  size_t dst = (size_t)row * D_;
  for (int d = threadIdx.x; d < D_; d += 256) g[dst + d] = h[src + d];
}

// ---------------------------------------------------------------- launcher
extern "C" void kernel_launch(void* const* d_in, const int* in_sizes, int n_in,
                              void* d_out, int out_size, void* d_ws, size_t ws_size,
                              hipStream_t stream) {
  const int* x = (const int*)d_in[0];
  const int* cpos = (const int*)d_in[1];
  const float* emb = (const float*)d_in[2];
  const float* rel = (const float*)d_in[3];
  const float* Wq = (const float*)d_in[4];
  const float* bq = (const float*)d_in[5];
  const float* Wk = (const float*)d_in[6];
  const float* bk = (const float*)d_in[7];
  const float* Wv = (const float*)d_in[8];
  const float* bv = (const float*)d_in[9];
  const float* Wo = (const float*)d_in[10];
  const float* bo = (const float*)d_in[11];
  const float* ln1s = (const float*)d_in[12];
  const float* ln1b = (const float*)d_in[13];
  const float* W1 = (const float*)d_in[14];
  const float* b1 = (const float*)d_in[15];
  const float* W2 = (const float*)d_in[16];
  const float* b2 = (const float*)d_in[17];
  const float* ln2s = (const float*)d_in[18];
  const float* ln2b = (const float*)d_in[19];
  const float* Wout = (const float*)d_in[20];
  const float* bout = (const float*)d_in[21];
  const float* Wc = (const float*)d_in[22];
  const float* bc = (const float*)d_in[23];

  const size_t SZ = (size_t)BT_ * D_;  // 4M elems
  float* h = (float*)d_ws;
  float* y = h + SZ;
  ushort_t* h_bf = (ushort_t*)(y + SZ);
  ushort_t* q_bf = h_bf + SZ;
  ushort_t* k_bf = q_bf + SZ;
  ushort_t* v_bf = k_bf + SZ;
  ushort_t* o_bf = v_bf + SZ;
  ushort_t* mid_bf = o_bf + SZ;                       // BT*F
  ushort_t* wt = mid_bf + (size_t)BT_ * F_;           // weight pool
  const size_t WPROJ = (size_t)D_ * D_;               // 262144
  const size_t WFFN = (size_t)D_ * F_;                // 1048576
  ushort_t* wqT = wt;
  ushort_t* wkT = wqT + 12 * WPROJ;
  ushort_t* wvT = wkT + 12 * WPROJ;
  ushort_t* woT = wvT + 12 * WPROJ;
  ushort_t* w1T = woT + 12 * WPROJ;
  ushort_t* w2T = w1T + 12 * WFFN;
  ushort_t* woutT = w2T + 12 * WFFN;
  ushort_t* wcT = woutT + WFFN;
  float* gath = (float*)(wcT + (size_t)D_ * C_);      // B*M x D f32
  float* out = (float*)d_out;

  // weight pre-pass: (K,N) f32 -> (N,K) bf16
  for (int l = 0; l < L_; ++l) {
    transpose_bf16<<<dim3(D_ / 32, D_ / 32), 256, 0, stream>>>(Wq + (size_t)l * WPROJ, wqT + l * WPROJ, D_, D_);
    transpose_bf16<<<dim3(D_ / 32, D_ / 32), 256, 0, stream>>>(Wk + (size_t)l * WPROJ, wkT + l * WPROJ, D_, D_);
    transpose_bf16<<<dim3(D_ / 32, D_ / 32), 256, 0, stream>>>(Wv + (size_t)l * WPROJ, wvT + l * WPROJ, D_, D_);
    transpose_bf16<<<dim3(D_ / 32, D_ / 32), 256, 0, stream>>>(Wo + (size_t)l * WPROJ, woT + l * WPROJ, D_, D_);
    transpose_bf16<<<dim3(F_ / 32, D_ / 32), 256, 0, stream>>>(W1 + (size_t)l * WFFN, w1T + l * WFFN, D_, F_);
    transpose_bf16<<<dim3(D_ / 32, F_ / 32), 256, 0, stream>>>(W2 + (size_t)l * WFFN, w2T + l * WFFN, F_, D_);
  }
  transpose_bf16<<<dim3(V_ / 32, D_ / 32), 256, 0, stream>>>(Wout, woutT, D_, V_);
  transpose_bf16<<<dim3(C_ / 32, D_ / 32), 256, 0, stream>>>(Wc, wcT, D_, C_);

  embed_kernel<<<BT_, 256, 0, stream>>>(x, emb, h, h_bf);

  dim3 gProj(D_ / 128, BT_ / 128);   // (4,64)
  dim3 gF1(F_ / 128, BT_ / 128);     // (16,64)
  dim3 gOut(V_ / 128, BT_ / 128);    // (16,64)

  for (int l = 0; l < L_; ++l) {
    gemm_mfma<1, 0><<<gProj, 256, 0, stream>>>(h_bf, wqT + l * WPROJ, bq + l * D_, q_bf, BT_, D_, D_);
    gemm_mfma<1, 0><<<gProj, 256, 0, stream>>>(h_bf, wkT + l * WPROJ, bk + l * D_, k_bf, BT_, D_, D_);
    gemm_mfma<1, 0><<<gProj, 256, 0, stream>>>(h_bf, wvT + l * WPROJ, bv + l * D_, v_bf, BT_, D_, D_);
    attn_tiled<<<B_ * H_ * (TT / 64), 256, 0, stream>>>(q_bf, k_bf, v_bf, rel + (size_t)l * NR_ * HD_, o_bf);
    gemm_mfma<0, 0><<<gProj, 256, 0, stream>>>(o_bf, woT + l * WPROJ, bo + l * D_, y, BT_, D_, D_);
    ln_res_kernel<<<BT_, 256, 0, stream>>>(h, y, ln1s + l * D_, ln1b + l * D_, h_bf);
    gemm_mfma<1, 1><<<gF1, 256, 0, stream>>>(h_bf, w1T + l * WFFN, b1 + l * F_, mid_bf, BT_, F_, D_);
    gemm_mfma<0, 0><<<gProj, 256, 0, stream>>>(mid_bf, w2T + l * WFFN, b2 + l * D_, y, BT_, D_, F_);
    ln_res_kernel<<<BT_, 256, 0, stream>>>(h, y, ln2s + l * D_, ln2b + l * D_, h_bf);
  }

  gemm_mfma<0, 0><<<gOut, 256, 0, stream>>>(h_bf, woutT, bout, out, BT_, V_, D_);
  gather_kernel<<<B_ * M_, 256, 0, stream>>>(h, cpos, gath);
  gemm_bias<0><<<dim3(1, (B_ * M_) / 64), 256, 0, stream>>>(gath, Wc, bc, out + (size_t)BT_ * V_,
                                                            B_ * M_, C_, D_);
}

// Round 6
// 3748.763 us; speedup vs baseline: 14.4008x; 2.1020x over previous
//
#include <hip/hip_runtime.h>
#include <hip/hip_bf16.h>
#include <cstddef>

constexpr int B_ = 8, TT = 1024, H_ = 8, HD_ = 64, D_ = 512, F_ = 2048;
constexpr int L_ = 12, R_ = 1024, NR_ = 2049, C_ = 64, M_ = 128, V_ = 2048;
constexpr int BT_ = B_ * TT;  // 8192

typedef short bf16x8_t __attribute__((ext_vector_type(8)));
typedef float f32x4_t __attribute__((ext_vector_type(4)));
typedef unsigned short ushort_t;

__device__ __forceinline__ float b2f(unsigned int u16) {
  return __uint_as_float(u16 << 16);
}
__device__ __forceinline__ ushort_t f2b(float f) {
  __hip_bfloat16 h = __float2bfloat16(f);
  return *reinterpret_cast<ushort_t*>(&h);
}

// ---------------------------------------------------------------- weight transpose+convert: src (K,N) f32 -> dst (N,K) bf16
__global__ __launch_bounds__(256) void transpose_bf16(const float* __restrict__ src,
                                                      ushort_t* __restrict__ dst,
                                                      int K, int N) {
  __shared__ float t[32][33];
  int k0 = blockIdx.y * 32, n0 = blockIdx.x * 32;
  int r = threadIdx.x >> 3, c4 = (threadIdx.x & 7) * 4;
  float4 vv = *(const float4*)(src + (size_t)(k0 + r) * N + n0 + c4);
  t[r][c4] = vv.x; t[r][c4 + 1] = vv.y; t[r][c4 + 2] = vv.z; t[r][c4 + 3] = vv.w;
  __syncthreads();
  ushort4 w;
  w.x = f2b(t[c4 + 0][r]); w.y = f2b(t[c4 + 1][r]);
  w.z = f2b(t[c4 + 2][r]); w.w = f2b(t[c4 + 3][r]);
  *(ushort4*)(dst + (size_t)(n0 + r) * K + k0 + c4) = w;
}

// ---------------------------------------------------------------- embedding + posenc (f32 + bf16 out)
__global__ void embed_kernel(const int* __restrict__ x, const float* __restrict__ emb,
                             float* __restrict__ h, ushort_t* __restrict__ h_bf) {
  int bt = blockIdx.x;
  int t = bt & (TT - 1);
  int tok = x[bt];
  const float c = -9.210340371976184f / 512.0f;
  size_t base = (size_t)bt * D_;
  size_t ebase = (size_t)tok * D_;
  for (int d = threadIdx.x; d < D_; d += 256) {
    int i = d >> 1;
    float div = expf((float)(2 * i) * c);
    float arg = (float)t * div;
    float pe = (d & 1) ? cosf(arg) : sinf(arg);
    float vv = emb[ebase + d] * 22.627416997969522f + pe;
    h[base + d] = vv;
    h_bf[base + d] = f2b(vv);
  }
}

// ---------------------------------------------------------------- MFMA GEMM: C = A@B + bias
template <int OUT_BF16, int RELU>
__global__ __launch_bounds__(256) void gemm_mfma(const ushort_t* __restrict__ A,
                                                 const ushort_t* __restrict__ Bt,
                                                 const float* __restrict__ bias,
                                                 void* __restrict__ Cout,
                                                 int Mm, int N, int K) {
  __shared__ ushort_t As[128 * 32];
  __shared__ ushort_t Bs[128 * 32];
  int tid = threadIdx.x;
  int m0 = blockIdx.y * 128, n0 = blockIdx.x * 128;
  int lane = tid & 63, wid = tid >> 6;
  int wr = wid >> 1, wc = wid & 1;

  f32x4_t acc[4][4];
#pragma unroll
  for (int mi = 0; mi < 4; ++mi)
#pragma unroll
    for (int ni = 0; ni < 4; ++ni) acc[mi][ni] = (f32x4_t){0.f, 0.f, 0.f, 0.f};

  int c0 = tid, c1 = tid + 256;
  int ar0 = c0 >> 2, ap0 = c0 & 3, akg0 = ap0 ^ ((ar0 >> 1) & 3);
  int ar1 = c1 >> 2, ap1 = c1 & 3, akg1 = ap1 ^ ((ar1 >> 1) & 3);
  const ushort_t* Arow0 = A + (size_t)(m0 + ar0) * K + akg0 * 8;
  const ushort_t* Arow1 = A + (size_t)(m0 + ar1) * K + akg1 * 8;
  const ushort_t* Brow0 = Bt + (size_t)(n0 + ar0) * K + akg0 * 8;
  const ushort_t* Brow1 = Bt + (size_t)(n0 + ar1) * K + akg1 * 8;

  uint4 ra0 = *(const uint4*)(Arow0);
  uint4 ra1 = *(const uint4*)(Arow1);
  uint4 rb0 = *(const uint4*)(Brow0);
  uint4 rb1 = *(const uint4*)(Brow1);

  int NT = K >> 5;
  int kg = lane >> 4, rl = lane & 15;
  for (int kt = 0; kt < NT; ++kt) {
    __syncthreads();
    *(uint4*)&As[ar0 * 32 + ap0 * 8] = ra0;
    *(uint4*)&As[ar1 * 32 + ap1 * 8] = ra1;
    *(uint4*)&Bs[ar0 * 32 + ap0 * 8] = rb0;
    *(uint4*)&Bs[ar1 * 32 + ap1 * 8] = rb1;
    __syncthreads();
    if (kt + 1 < NT) {
      int ko = (kt + 1) << 5;
      ra0 = *(const uint4*)(Arow0 + ko);
      ra1 = *(const uint4*)(Arow1 + ko);
      rb0 = *(const uint4*)(Brow0 + ko);
      rb1 = *(const uint4*)(Brow1 + ko);
    }
    bf16x8_t fa[4], fb[4];
#pragma unroll
    for (int mi = 0; mi < 4; ++mi) {
      int r = wr * 64 + mi * 16 + rl;
      fa[mi] = *(bf16x8_t*)&As[r * 32 + ((kg ^ ((r >> 1) & 3)) << 3)];
    }
#pragma unroll
    for (int ni = 0; ni < 4; ++ni) {
      int r = wc * 64 + ni * 16 + rl;
      fb[ni] = *(bf16x8_t*)&Bs[r * 32 + ((kg ^ ((r >> 1) & 3)) << 3)];
    }
#pragma unroll
    for (int mi = 0; mi < 4; ++mi)
#pragma unroll
      for (int ni = 0; ni < 4; ++ni)
        acc[mi][ni] = __builtin_amdgcn_mfma_f32_16x16x32_bf16(fa[mi], fb[ni], acc[mi][ni], 0, 0, 0);
  }

  int rg = lane >> 4;
#pragma unroll
  for (int ni = 0; ni < 4; ++ni) {
    int col = n0 + wc * 64 + ni * 16 + rl;
    float bv = bias[col];
#pragma unroll
    for (int mi = 0; mi < 4; ++mi) {
      int row0 = m0 + wr * 64 + mi * 16 + rg * 4;
#pragma unroll
      for (int r = 0; r < 4; ++r) {
        float vv = acc[mi][ni][r] + bv;
        if (RELU) vv = fmaxf(vv, 0.0f);
        if (OUT_BF16)
          ((ushort_t*)Cout)[(size_t)(row0 + r) * N + col] = f2b(vv);
        else
          ((float*)Cout)[(size_t)(row0 + r) * N + col] = vv;
      }
    }
  }
}

// ---------------------------------------------------------------- legacy f32 GEMM (chord head only)
template <int RELU>
__global__ __launch_bounds__(256) void gemm_bias(const float* __restrict__ A,
                                                 const float* __restrict__ W,
                                                 const float* __restrict__ bias,
                                                 float* __restrict__ Cm,
                                                 int Mm, int N, int K) {
  __shared__ float As[64][17];
  __shared__ float Bs[16][65];
  int tid = threadIdx.x;
  int tx = tid & 15, ty = tid >> 4;
  int row0 = blockIdx.y * 64, col0 = blockIdx.x * 64;
  float acc[4][4] = {};
  int ra = tid >> 4, ca = tid & 15;
  int rb = tid >> 6, cb = tid & 63;
  for (int k0 = 0; k0 < K; k0 += 16) {
    for (int rr = ra; rr < 64; rr += 16)
      As[rr][ca] = A[(size_t)(row0 + rr) * K + k0 + ca];
    for (int rr = rb; rr < 16; rr += 4)
      Bs[rr][cb] = W[(size_t)(k0 + rr) * N + col0 + cb];
    __syncthreads();
#pragma unroll
    for (int kk = 0; kk < 16; ++kk) {
      float a[4], bb[4];
#pragma unroll
      for (int i = 0; i < 4; ++i) a[i] = As[ty * 4 + i][kk];
#pragma unroll
      for (int j = 0; j < 4; ++j) bb[j] = Bs[kk][tx * 4 + j];
#pragma unroll
      for (int i = 0; i < 4; ++i)
#pragma unroll
        for (int j = 0; j < 4; ++j) acc[i][j] += a[i] * bb[j];
    }
    __syncthreads();
  }
#pragma unroll
  for (int i = 0; i < 4; ++i) {
#pragma unroll
    for (int j = 0; j < 4; ++j) {
      float vv = acc[i][j] + bias[col0 + tx * 4 + j];
      if (RELU) vv = fmaxf(vv, 0.0f);
      Cm[(size_t)(row0 + ty * 4 + i) * N + col0 + tx * 4 + j] = vv;
    }
  }
}

// ---------------------------------------------------------------- MFMA causal attention with fused rel-pos
// Block: 64 q-rows of one (b,h), 4 waves x 16 rows. K-tiles of 64.
// S(r,c) = qs(r).(k(c) + rel(c-r+R)); rel via rp(r,p)=qs(r).relwin(p), p=c_l-r_l+15.
__global__ __launch_bounds__(256) void attn_mfma(const ushort_t* __restrict__ q,
                                                 const ushort_t* __restrict__ k,
                                                 const ushort_t* __restrict__ v,
                                                 const float* __restrict__ rel,
                                                 ushort_t* __restrict__ o) {
  __shared__ ushort_t Qs[64 * 64];    // 8 KB, swizzled granules
  __shared__ ushort_t Ks[64 * 64];    // 8 KB
  __shared__ ushort_t Vt[64 * 64];    // 8 KB, [d][kk]
  __shared__ ushort_t Rl[128 * 64];   // 16 KB, rel window rows
  __shared__ ushort_t Ps[4][16 * 64]; // 8 KB, per-wave P strips

  int blk = blockIdx.x;
  int qt = blk & 15, bh = blk >> 4;
  int hh = bh & 7, b = bh >> 3;
  int t0 = qt << 6;
  int tid = threadIdx.x;
  int lane = tid & 63, w = tid >> 6;
  int lo = lane & 15, hi = lane >> 4;

  const ushort_t* qg = q + ((size_t)(b * TT + t0)) * D_ + hh * HD_;
  const ushort_t* kg = k + ((size_t)b * TT) * D_ + hh * HD_;
  const ushort_t* vg = v + ((size_t)b * TT) * D_ + hh * HD_;

  // ---- stage Q once, scaled by 1/8 (exact in bf16 path via float)
  for (int idx = tid; idx < 512; idx += 256) {
    int row = idx >> 3, gg = idx & 7;
    uint4 u = *(const uint4*)(qg + (size_t)row * D_ + gg * 8);
    unsigned int uw[4] = {u.x, u.y, u.z, u.w};
    unsigned int ow[4];
#pragma unroll
    for (int j = 0; j < 4; ++j) {
      float f0 = b2f(uw[j] & 0xffffu) * 0.125f;
      float f1 = b2f(uw[j] >> 16) * 0.125f;
      ow[j] = (unsigned int)f2b(f0) | ((unsigned int)f2b(f1) << 16);
    }
    *(uint4*)&Qs[row * 64 + ((gg ^ (row & 7)) << 3)] = make_uint4(ow[0], ow[1], ow[2], ow[3]);
  }
  __syncthreads();

  // Q A-fragments for this wave: row = 16w+lo, k-granules hi and hi+4
  bf16x8_t faq0 = *(bf16x8_t*)&Qs[(16 * w + lo) * 64 + ((hi ^ (lo & 7)) << 3)];
  bf16x8_t faq1 = *(bf16x8_t*)&Qs[(16 * w + lo) * 64 + (((hi + 4) ^ (lo & 7)) << 3)];

  f32x4_t acc_o[4];
#pragma unroll
  for (int nd = 0; nd < 4; ++nd) acc_o[nd] = (f32x4_t){0.f, 0.f, 0.f, 0.f};
  float mrow[4] = {-1e30f, -1e30f, -1e30f, -1e30f};
  float lrow[4] = {0.f, 0.f, 0.f, 0.f};

  int nkt = (t0 >> 6) + 1;
  for (int kt = 0; kt < nkt; ++kt) {
    int k0 = kt << 6;
    __syncthreads();  // previous PV done before restage
    // ---- stage K (bf16 copy)
    for (int idx = tid; idx < 512; idx += 256) {
      int row = idx >> 3, gg = idx & 7;
      uint4 u = *(const uint4*)(kg + (size_t)(k0 + row) * D_ + gg * 8);
      *(uint4*)&Ks[row * 64 + ((gg ^ (row & 7)) << 3)] = u;
    }
    // ---- stage V transposed: Vt[d][kk], bank-staggered scalar stores
    for (int idx = tid; idx < 512; idx += 256) {
      int kk = idx >> 3, gd = idx & 7;
      uint4 u = *(const uint4*)(vg + (size_t)(k0 + kk) * D_ + gd * 8);
      unsigned int uw[4] = {u.x, u.y, u.z, u.w};
      int st = tid & 7;
#pragma unroll
      for (int ee = 0; ee < 8; ++ee) {
        int e = (ee + st) & 7;
        int eh = e >> 1;
        unsigned int word = (eh == 0) ? uw[0] : (eh == 1) ? uw[1] : (eh == 2) ? uw[2] : uw[3];
        ushort_t val = (e & 1) ? (ushort_t)(word >> 16) : (ushort_t)(word & 0xffffu);
        int d = gd * 8 + e;
        Vt[d * 64 + (((kk >> 3) ^ (d & 7)) << 3) + (kk & 7)] = val;
      }
    }
    // ---- stage rel window: union rows u=0..127, j_global = k0 - t0 + 961 + u
    {
      const float* rbase = rel + (size_t)(k0 - t0 + 961) * 64;
      for (int idx = tid; idx < 1024; idx += 256) {
        int u_ = idx >> 3, gg = idx & 7;
        const float* src = rbase + (size_t)u_ * 64 + gg * 8;
        float4 f0 = *(const float4*)(src);
        float4 f1 = *(const float4*)(src + 4);
        unsigned int ow[4];
        ow[0] = (unsigned int)f2b(f0.x) | ((unsigned int)f2b(f0.y) << 16);
        ow[1] = (unsigned int)f2b(f0.z) | ((unsigned int)f2b(f0.w) << 16);
        ow[2] = (unsigned int)f2b(f1.x) | ((unsigned int)f2b(f1.y) << 16);
        ow[3] = (unsigned int)f2b(f1.z) | ((unsigned int)f2b(f1.w) << 16);
        *(uint4*)&Rl[u_ * 64 + ((gg ^ (u_ & 7)) << 3)] = make_uint4(ow[0], ow[1], ow[2], ow[3]);
      }
    }
    __syncthreads();

    // ---- QK^T: acc_s[nc], S rows 16w+rl, cols k0+16nc+lo
    f32x4_t acc_s[4], acc_r[5];
#pragma unroll
    for (int nc = 0; nc < 4; ++nc) acc_s[nc] = (f32x4_t){0.f, 0.f, 0.f, 0.f};
#pragma unroll
    for (int pt = 0; pt < 5; ++pt) acc_r[pt] = (f32x4_t){0.f, 0.f, 0.f, 0.f};

#pragma unroll
    for (int nc = 0; nc < 4; ++nc) {
      int row = 16 * nc + lo;
      bf16x8_t fb0 = *(bf16x8_t*)&Ks[row * 64 + ((hi ^ (lo & 7)) << 3)];
      bf16x8_t fb1 = *(bf16x8_t*)&Ks[row * 64 + (((hi + 4) ^ (lo & 7)) << 3)];
      acc_s[nc] = __builtin_amdgcn_mfma_f32_16x16x32_bf16(faq0, fb0, acc_s[nc], 0, 0, 0);
      acc_s[nc] = __builtin_amdgcn_mfma_f32_16x16x32_bf16(faq1, fb1, acc_s[nc], 0, 0, 0);
    }
    // ---- rel: rp(rl, p), wave window starts at union row 48-16w
#pragma unroll
    for (int pt = 0; pt < 5; ++pt) {
      int row = 16 * (3 - w + pt) + lo;
      bf16x8_t fb0 = *(bf16x8_t*)&Rl[row * 64 + ((hi ^ (lo & 7)) << 3)];
      bf16x8_t fb1 = *(bf16x8_t*)&Rl[row * 64 + (((hi + 4) ^ (lo & 7)) << 3)];
      acc_r[pt] = __builtin_amdgcn_mfma_f32_16x16x32_bf16(faq0, fb0, acc_r[pt], 0, 0, 0);
      acc_r[pt] = __builtin_amdgcn_mfma_f32_16x16x32_bf16(faq1, fb1, acc_r[pt], 0, 0, 0);
    }

    bool islast = (kt == nkt - 1);
    // ---- gather rel (p = c_l - r_l + 15), mask, online softmax, P->LDS
#pragma unroll
    for (int g = 0; g < 4; ++g) {
      int rl = 4 * hi + g;
      int dd = lo + 15 - rl;             // in [0,30]
      int src = (lane & 48) | (dd & 15); // same hi-group, col dd&15
      bool carry = (dd & 16) != 0;
      float sh0 = __shfl(acc_r[0][g], src);
      float sh1 = __shfl(acc_r[1][g], src);
      float sh2 = __shfl(acc_r[2][g], src);
      float sh3 = __shfl(acc_r[3][g], src);
      float sh4 = __shfl(acc_r[4][g], src);
      float s0 = acc_s[0][g] + (carry ? sh1 : sh0);
      float s1 = acc_s[1][g] + (carry ? sh2 : sh1);
      float s2 = acc_s[2][g] + (carry ? sh3 : sh2);
      float s3 = acc_s[3][g] + (carry ? sh4 : sh3);
      if (islast) {  // k0 == t0: mask c_l > 16w + rl
        int rw = 16 * w + rl;
        if (lo > rw) s0 = -1e30f;
        if (16 + lo > rw) s1 = -1e30f;
        if (32 + lo > rw) s2 = -1e30f;
        if (48 + lo > rw) s3 = -1e30f;
      }
      float mx = fmaxf(fmaxf(s0, s1), fmaxf(s2, s3));
      mx = fmaxf(mx, __shfl_xor(mx, 1));
      mx = fmaxf(mx, __shfl_xor(mx, 2));
      mx = fmaxf(mx, __shfl_xor(mx, 4));
      mx = fmaxf(mx, __shfl_xor(mx, 8));
      float mnew = fmaxf(mrow[g], mx);
      float scale = __expf(mrow[g] - mnew);
      mrow[g] = mnew;
      float p0 = __expf(s0 - mnew);
      float p1 = __expf(s1 - mnew);
      float p2 = __expf(s2 - mnew);
      float p3 = __expf(s3 - mnew);
      float ls = p0 + p1 + p2 + p3;
      ls += __shfl_xor(ls, 1);
      ls += __shfl_xor(ls, 2);
      ls += __shfl_xor(ls, 4);
      ls += __shfl_xor(ls, 8);
      lrow[g] = lrow[g] * scale + ls;
      acc_o[0][g] *= scale; acc_o[1][g] *= scale;
      acc_o[2][g] *= scale; acc_o[3][g] *= scale;
      ushort_t* pr = &Ps[w][rl * 64];
      int rsw = rl & 7, l3 = lo >> 3, l7 = lo & 7;
      pr[(((0 + l3) ^ rsw) << 3) + l7] = f2b(p0);
      pr[(((2 + l3) ^ rsw) << 3) + l7] = f2b(p1);
      pr[(((4 + l3) ^ rsw) << 3) + l7] = f2b(p2);
      pr[(((6 + l3) ^ rsw) << 3) + l7] = f2b(p3);
    }

    // ---- PV: O(rl, d) += P(rl, kk) V(kk, d)
    bf16x8_t pa0 = *(bf16x8_t*)&Ps[w][lo * 64 + ((hi ^ (lo & 7)) << 3)];
    bf16x8_t pa1 = *(bf16x8_t*)&Ps[w][lo * 64 + (((hi + 4) ^ (lo & 7)) << 3)];
#pragma unroll
    for (int nd = 0; nd < 4; ++nd) {
      int row = 16 * nd + lo;
      bf16x8_t fb0 = *(bf16x8_t*)&Vt[row * 64 + ((hi ^ (lo & 7)) << 3)];
      bf16x8_t fb1 = *(bf16x8_t*)&Vt[row * 64 + (((hi + 4) ^ (lo & 7)) << 3)];
      acc_o[nd] = __builtin_amdgcn_mfma_f32_16x16x32_bf16(pa0, fb0, acc_o[nd], 0, 0, 0);
      acc_o[nd] = __builtin_amdgcn_mfma_f32_16x16x32_bf16(pa1, fb1, acc_o[nd], 0, 0, 0);
    }
  }

  // ---- output
  ushort_t* og = o + ((size_t)(b * TT + t0 + 16 * w)) * D_ + hh * HD_;
#pragma unroll
  for (int g = 0; g < 4; ++g) {
    int rl = 4 * hi + g;
    float inv = 1.0f / lrow[g];
#pragma unroll
    for (int nd = 0; nd < 4; ++nd)
      og[(size_t)rl * D_ + 16 * nd + lo] = f2b(acc_o[nd][g] * inv);
  }
}

// ---------------------------------------------------------------- residual + layernorm (f32 h in-place, bf16 copy)
__global__ __launch_bounds__(256) void ln_res_kernel(float* __restrict__ h,
                                                     const float* __restrict__ y,
                                                     const float* __restrict__ s,
                                                     const float* __restrict__ bvec,
                                                     ushort_t* __restrict__ h_bf) {
  int row = blockIdx.x;
  int tid = threadIdx.x;
  size_t base = (size_t)row * D_;
  float z0 = h[base + tid] + y[base + tid];
  float z1 = h[base + tid + 256] + y[base + tid + 256];
  __shared__ float r1[256], r2[256];
  r1[tid] = z0 + z1;
  r2[tid] = z0 * z0 + z1 * z1;
  __syncthreads();
  for (int off = 128; off > 0; off >>= 1) {
    if (tid < off) {
      r1[tid] += r1[tid + off];
      r2[tid] += r2[tid + off];
    }
    __syncthreads();
  }
  float mu = r1[0] * (1.0f / 512.0f);
  float var = r2[0] * (1.0f / 512.0f) - mu * mu;
  float rs = rsqrtf(var + 1e-5f);
  float o0 = (z0 - mu) * rs * s[tid] + bvec[tid];
  float o1 = (z1 - mu) * rs * s[tid + 256] + bvec[tid + 256];
  h[base + tid] = o0;
  h[base + tid + 256] = o1;
  h_bf[base + tid] = f2b(o0);
  h_bf[base + tid + 256] = f2b(o1);
}

// ---------------------------------------------------------------- chord gather (f32)
__global__ void gather_kernel(const float* __restrict__ h, const int* __restrict__ pos,
                              float* __restrict__ g) {
  int row = blockIdx.x;
  int b = row >> 7;
  int p = pos[row];
  if (p < 0) p = 0;
  size_t src = ((size_t)(b * TT + p)) * D_;
  size_t dst = (size_t)row * D_;
  for (int d = threadIdx.x; d < D_; d += 256) g[dst + d] = h[src + d];
}

// ---------------------------------------------------------------- launcher
extern "C" void kernel_launch(void* const* d_in, const int* in_sizes, int n_in,
                              void* d_out, int out_size, void* d_ws, size_t ws_size,
                              hipStream_t stream) {
  const int* x = (const int*)d_in[0];
  const int* cpos = (const int*)d_in[1];
  const float* emb = (const float*)d_in[2];
  const float* rel = (const float*)d_in[3];
  const float* Wq = (const float*)d_in[4];
  const float* bq = (const float*)d_in[5];
  const float* Wk = (const float*)d_in[6];
  const float* bk = (const float*)d_in[7];
  const float* Wv = (const float*)d_in[8];
  const float* bv = (const float*)d_in[9];
  const float* Wo = (const float*)d_in[10];
  const float* bo = (const float*)d_in[11];
  const float* ln1s = (const float*)d_in[12];
  const float* ln1b = (const float*)d_in[13];
  const float* W1 = (const float*)d_in[14];
  const float* b1 = (const float*)d_in[15];
  const float* W2 = (const float*)d_in[16];
  const float* b2 = (const float*)d_in[17];
  const float* ln2s = (const float*)d_in[18];
  const float* ln2b = (const float*)d_in[19];
  const float* Wout = (const float*)d_in[20];
  const float* bout = (const float*)d_in[21];
  const float* Wc = (const float*)d_in[22];
  const float* bc = (const float*)d_in[23];

  const size_t SZ = (size_t)BT_ * D_;  // 4M elems
  float* h = (float*)d_ws;
  float* y = h + SZ;
  ushort_t* h_bf = (ushort_t*)(y + SZ);
  ushort_t* q_bf = h_bf + SZ;
  ushort_t* k_bf = q_bf + SZ;
  ushort_t* v_bf = k_bf + SZ;
  ushort_t* o_bf = v_bf + SZ;
  ushort_t* mid_bf = o_bf + SZ;                       // BT*F
  ushort_t* wt = mid_bf + (size_t)BT_ * F_;           // weight pool
  const size_t WPROJ = (size_t)D_ * D_;               // 262144
  const size_t WFFN = (size_t)D_ * F_;                // 1048576
  ushort_t* wqT = wt;
  ushort_t* wkT = wqT + 12 * WPROJ;
  ushort_t* wvT = wkT + 12 * WPROJ;
  ushort_t* woT = wvT + 12 * WPROJ;
  ushort_t* w1T = woT + 12 * WPROJ;
  ushort_t* w2T = w1T + 12 * WFFN;
  ushort_t* woutT = w2T + 12 * WFFN;
  ushort_t* wcT = woutT + WFFN;
  float* gath = (float*)(wcT + (size_t)D_ * C_);      // B*M x D f32
  float* out = (float*)d_out;

  // weight pre-pass: (K,N) f32 -> (N,K) bf16
  for (int l = 0; l < L_; ++l) {
    transpose_bf16<<<dim3(D_ / 32, D_ / 32), 256, 0, stream>>>(Wq + (size_t)l * WPROJ, wqT + l * WPROJ, D_, D_);
    transpose_bf16<<<dim3(D_ / 32, D_ / 32), 256, 0, stream>>>(Wk + (size_t)l * WPROJ, wkT + l * WPROJ, D_, D_);
    transpose_bf16<<<dim3(D_ / 32, D_ / 32), 256, 0, stream>>>(Wv + (size_t)l * WPROJ, wvT + l * WPROJ, D_, D_);
    transpose_bf16<<<dim3(D_ / 32, D_ / 32), 256, 0, stream>>>(Wo + (size_t)l * WPROJ, woT + l * WPROJ, D_, D_);
    transpose_bf16<<<dim3(F_ / 32, D_ / 32), 256, 0, stream>>>(W1 + (size_t)l * WFFN, w1T + l * WFFN, D_, F_);
    transpose_bf16<<<dim3(D_ / 32, F_ / 32), 256, 0, stream>>>(W2 + (size_t)l * WFFN, w2T + l * WFFN, F_, D_);
  }
  transpose_bf16<<<dim3(V_ / 32, D_ / 32), 256, 0, stream>>>(Wout, woutT, D_, V_);
  transpose_bf16<<<dim3(C_ / 32, D_ / 32), 256, 0, stream>>>(Wc, wcT, D_, C_);

  embed_kernel<<<BT_, 256, 0, stream>>>(x, emb, h, h_bf);

  dim3 gProj(D_ / 128, BT_ / 128);   // (4,64)
  dim3 gF1(F_ / 128, BT_ / 128);     // (16,64)
  dim3 gOut(V_ / 128, BT_ / 128);    // (16,64)

  for (int l = 0; l < L_; ++l) {
    gemm_mfma<1, 0><<<gProj, 256, 0, stream>>>(h_bf, wqT + l * WPROJ, bq + l * D_, q_bf, BT_, D_, D_);
    gemm_mfma<1, 0><<<gProj, 256, 0, stream>>>(h_bf, wkT + l * WPROJ, bk + l * D_, k_bf, BT_, D_, D_);
    gemm_mfma<1, 0><<<gProj, 256, 0, stream>>>(h_bf, wvT + l * WPROJ, bv + l * D_, v_bf, BT_, D_, D_);
    attn_mfma<<<B_ * H_ * (TT / 64), 256, 0, stream>>>(q_bf, k_bf, v_bf, rel + (size_t)l * NR_ * HD_, o_bf);
    gemm_mfma<0, 0><<<gProj, 256, 0, stream>>>(o_bf, woT + l * WPROJ, bo + l * D_, y, BT_, D_, D_);
    ln_res_kernel<<<BT_, 256, 0, stream>>>(h, y, ln1s + l * D_, ln1b + l * D_, h_bf);
    gemm_mfma<1, 1><<<gF1, 256, 0, stream>>>(h_bf, w1T + l * WFFN, b1 + l * F_, mid_bf, BT_, F_, D_);
    gemm_mfma<0, 0><<<gProj, 256, 0, stream>>>(mid_bf, w2T + l * WFFN, b2 + l * D_, y, BT_, D_, F_);
    ln_res_kernel<<<BT_, 256, 0, stream>>>(h, y, ln2s + l * D_, ln2b + l * D_, h_bf);
  }

  gemm_mfma<0, 0><<<gOut, 256, 0, stream>>>(h_bf, woutT, bout, out, BT_, V_, D_);
  gather_kernel<<<B_ * M_, 256, 0, stream>>>(h, cpos, gath);
  gemm_bias<0><<<dim3(1, (B_ * M_) / 64), 256, 0, stream>>>(gath, Wc, bc, out + (size_t)BT_ * V_,
                                                            B_ * M_, C_, D_);
}

// Round 7
// 3180.083 us; speedup vs baseline: 16.9760x; 1.1788x over previous
//
#include <hip/hip_runtime.h>
#include <hip/hip_bf16.h>
#include <cstddef>

constexpr int B_ = 8, TT = 1024, H_ = 8, HD_ = 64, D_ = 512, F_ = 2048;
constexpr int L_ = 12, R_ = 1024, NR_ = 2049, C_ = 64, M_ = 128, V_ = 2048;
constexpr int BT_ = B_ * TT;  // 8192

typedef short bf16x8_t __attribute__((ext_vector_type(8)));
typedef float f32x4_t __attribute__((ext_vector_type(4)));
typedef unsigned short ushort_t;

__device__ __forceinline__ float b2f(unsigned int u16) {
  return __uint_as_float(u16 << 16);
}
__device__ __forceinline__ ushort_t f2b(float f) {
  __hip_bfloat16 h = __float2bfloat16(f);
  return *reinterpret_cast<ushort_t*>(&h);
}

// ---------------------------------------------------------------- weight transpose+convert: src (K,N) f32 -> dst (N,K) bf16
__global__ __launch_bounds__(256) void transpose_bf16(const float* __restrict__ src,
                                                      ushort_t* __restrict__ dst,
                                                      int K, int N) {
  __shared__ float t[32][33];
  int k0 = blockIdx.y * 32, n0 = blockIdx.x * 32;
  int r = threadIdx.x >> 3, c4 = (threadIdx.x & 7) * 4;
  float4 vv = *(const float4*)(src + (size_t)(k0 + r) * N + n0 + c4);
  t[r][c4] = vv.x; t[r][c4 + 1] = vv.y; t[r][c4 + 2] = vv.z; t[r][c4 + 3] = vv.w;
  __syncthreads();
  ushort4 w;
  w.x = f2b(t[c4 + 0][r]); w.y = f2b(t[c4 + 1][r]);
  w.z = f2b(t[c4 + 2][r]); w.w = f2b(t[c4 + 3][r]);
  *(ushort4*)(dst + (size_t)(n0 + r) * K + k0 + c4) = w;
}

// ---------------------------------------------------------------- rel f32 -> bf16 (all layers)
__global__ __launch_bounds__(256) void rel_convert(const float* __restrict__ rel,
                                                   ushort_t* __restrict__ rel_bf) {
  size_t idx = ((size_t)blockIdx.x * 256 + threadIdx.x) * 4;
  const size_t total = (size_t)L_ * NR_ * HD_;  // 1573632
  if (idx >= total) return;
  float4 f = *(const float4*)(rel + idx);
  ushort4 w;
  w.x = f2b(f.x); w.y = f2b(f.y); w.z = f2b(f.z); w.w = f2b(f.w);
  *(ushort4*)(rel_bf + idx) = w;
}

// ---------------------------------------------------------------- pack q/k/v biases -> bqkv[l][1536]
__global__ __launch_bounds__(256) void pack_bias(const float* __restrict__ bq,
                                                 const float* __restrict__ bk,
                                                 const float* __restrict__ bv,
                                                 float* __restrict__ bqkv) {
  int idx = blockIdx.x * 256 + threadIdx.x;
  if (idx >= L_ * 1536) return;
  int l = idx / 1536, c = idx - l * 1536;
  float v;
  if (c < 512) v = bq[l * 512 + c];
  else if (c < 1024) v = bk[l * 512 + (c - 512)];
  else v = bv[l * 512 + (c - 1024)];
  bqkv[idx] = v;
}

// ---------------------------------------------------------------- embedding + posenc (f32 + bf16 out)
__global__ void embed_kernel(const int* __restrict__ x, const float* __restrict__ emb,
                             float* __restrict__ h, ushort_t* __restrict__ h_bf) {
  int bt = blockIdx.x;
  int t = bt & (TT - 1);
  int tok = x[bt];
  const float c = -9.210340371976184f / 512.0f;
  size_t base = (size_t)bt * D_;
  size_t ebase = (size_t)tok * D_;
  for (int d = threadIdx.x; d < D_; d += 256) {
    int i = d >> 1;
    float div = expf((float)(2 * i) * c);
    float arg = (float)t * div;
    float pe = (d & 1) ? cosf(arg) : sinf(arg);
    float vv = emb[ebase + d] * 22.627416997969522f + pe;
    h[base + d] = vv;
    h_bf[base + d] = f2b(vv);
  }
}

// ---------------------------------------------------------------- MFMA GEMM: C = A@B + bias
template <int OUT_BF16, int RELU>
__global__ __launch_bounds__(256) void gemm_mfma(const ushort_t* __restrict__ A,
                                                 const ushort_t* __restrict__ Bt,
                                                 const float* __restrict__ bias,
                                                 void* __restrict__ Cout,
                                                 int Mm, int N, int K) {
  __shared__ ushort_t As[128 * 32];
  __shared__ ushort_t Bs[128 * 32];
  int tid = threadIdx.x;
  int m0 = blockIdx.y * 128, n0 = blockIdx.x * 128;
  int lane = tid & 63, wid = tid >> 6;
  int wr = wid >> 1, wc = wid & 1;

  f32x4_t acc[4][4];
#pragma unroll
  for (int mi = 0; mi < 4; ++mi)
#pragma unroll
    for (int ni = 0; ni < 4; ++ni) acc[mi][ni] = (f32x4_t){0.f, 0.f, 0.f, 0.f};

  int c0 = tid, c1 = tid + 256;
  int ar0 = c0 >> 2, ap0 = c0 & 3, akg0 = ap0 ^ ((ar0 >> 1) & 3);
  int ar1 = c1 >> 2, ap1 = c1 & 3, akg1 = ap1 ^ ((ar1 >> 1) & 3);
  const ushort_t* Arow0 = A + (size_t)(m0 + ar0) * K + akg0 * 8;
  const ushort_t* Arow1 = A + (size_t)(m0 + ar1) * K + akg1 * 8;
  const ushort_t* Brow0 = Bt + (size_t)(n0 + ar0) * K + akg0 * 8;
  const ushort_t* Brow1 = Bt + (size_t)(n0 + ar1) * K + akg1 * 8;

  uint4 ra0 = *(const uint4*)(Arow0);
  uint4 ra1 = *(const uint4*)(Arow1);
  uint4 rb0 = *(const uint4*)(Brow0);
  uint4 rb1 = *(const uint4*)(Brow1);

  int NT = K >> 5;
  int kg = lane >> 4, rl = lane & 15;
  for (int kt = 0; kt < NT; ++kt) {
    __syncthreads();
    *(uint4*)&As[ar0 * 32 + ap0 * 8] = ra0;
    *(uint4*)&As[ar1 * 32 + ap1 * 8] = ra1;
    *(uint4*)&Bs[ar0 * 32 + ap0 * 8] = rb0;
    *(uint4*)&Bs[ar1 * 32 + ap1 * 8] = rb1;
    __syncthreads();
    if (kt + 1 < NT) {
      int ko = (kt + 1) << 5;
      ra0 = *(const uint4*)(Arow0 + ko);
      ra1 = *(const uint4*)(Arow1 + ko);
      rb0 = *(const uint4*)(Brow0 + ko);
      rb1 = *(const uint4*)(Brow1 + ko);
    }
    bf16x8_t fa[4], fb[4];
#pragma unroll
    for (int mi = 0; mi < 4; ++mi) {
      int r = wr * 64 + mi * 16 + rl;
      fa[mi] = *(bf16x8_t*)&As[r * 32 + ((kg ^ ((r >> 1) & 3)) << 3)];
    }
#pragma unroll
    for (int ni = 0; ni < 4; ++ni) {
      int r = wc * 64 + ni * 16 + rl;
      fb[ni] = *(bf16x8_t*)&Bs[r * 32 + ((kg ^ ((r >> 1) & 3)) << 3)];
    }
#pragma unroll
    for (int mi = 0; mi < 4; ++mi)
#pragma unroll
      for (int ni = 0; ni < 4; ++ni)
        acc[mi][ni] = __builtin_amdgcn_mfma_f32_16x16x32_bf16(fa[mi], fb[ni], acc[mi][ni], 0, 0, 0);
  }

  int rg = lane >> 4;
#pragma unroll
  for (int ni = 0; ni < 4; ++ni) {
    int col = n0 + wc * 64 + ni * 16 + rl;
    float bv = bias[col];
#pragma unroll
    for (int mi = 0; mi < 4; ++mi) {
      int row0 = m0 + wr * 64 + mi * 16 + rg * 4;
#pragma unroll
      for (int r = 0; r < 4; ++r) {
        float vv = acc[mi][ni][r] + bv;
        if (RELU) vv = fmaxf(vv, 0.0f);
        if (OUT_BF16)
          ((ushort_t*)Cout)[(size_t)(row0 + r) * N + col] = f2b(vv);
        else
          ((float*)Cout)[(size_t)(row0 + r) * N + col] = vv;
      }
    }
  }
}

// ---------------------------------------------------------------- legacy f32 GEMM (chord head only)
template <int RELU>
__global__ __launch_bounds__(256) void gemm_bias(const float* __restrict__ A,
                                                 const float* __restrict__ W,
                                                 const float* __restrict__ bias,
                                                 float* __restrict__ Cm,
                                                 int Mm, int N, int K) {
  __shared__ float As[64][17];
  __shared__ float Bs[16][65];
  int tid = threadIdx.x;
  int tx = tid & 15, ty = tid >> 4;
  int row0 = blockIdx.y * 64, col0 = blockIdx.x * 64;
  float acc[4][4] = {};
  int ra = tid >> 4, ca = tid & 15;
  int rb = tid >> 6, cb = tid & 63;
  for (int k0 = 0; k0 < K; k0 += 16) {
    for (int rr = ra; rr < 64; rr += 16)
      As[rr][ca] = A[(size_t)(row0 + rr) * K + k0 + ca];
    for (int rr = rb; rr < 16; rr += 4)
      Bs[rr][cb] = W[(size_t)(k0 + rr) * N + col0 + cb];
    __syncthreads();
#pragma unroll
    for (int kk = 0; kk < 16; ++kk) {
      float a[4], bb[4];
#pragma unroll
      for (int i = 0; i < 4; ++i) a[i] = As[ty * 4 + i][kk];
#pragma unroll
      for (int j = 0; j < 4; ++j) bb[j] = Bs[kk][tx * 4 + j];
#pragma unroll
      for (int i = 0; i < 4; ++i)
#pragma unroll
        for (int j = 0; j < 4; ++j) acc[i][j] += a[i] * bb[j];
    }
    __syncthreads();
  }
#pragma unroll
  for (int i = 0; i < 4; ++i) {
#pragma unroll
    for (int j = 0; j < 4; ++j) {
      float vv = acc[i][j] + bias[col0 + tx * 4 + j];
      if (RELU) vv = fmaxf(vv, 0.0f);
      Cm[(size_t)(row0 + ty * 4 + i) * N + col0 + tx * 4 + j] = vv;
    }
  }
}

// ---------------------------------------------------------------- MFMA causal attention with fused rel-pos
// Block: 64 q-rows of one (b,h), 4 waves x 16 rows. K-tiles of 64.
// qkv packed (BT,1536): q|k|v segments. rel_bf (NR,64) bf16 for this layer.
__global__ __launch_bounds__(256) void attn_mfma(const ushort_t* __restrict__ qkv,
                                                 const ushort_t* __restrict__ rel_bf,
                                                 ushort_t* __restrict__ o) {
  __shared__ ushort_t QPs[64 * 64];  // 8 KB: Q during prologue, P strips in loop
  __shared__ ushort_t Ks[64 * 64];   // 8 KB
  __shared__ ushort_t Vt[64 * 64];   // 8 KB, [d][kk]
  __shared__ ushort_t Rl[128 * 64];  // 16 KB rolling rel window

  int blk = blockIdx.x;
  // balanced qt mapping: bijective per (b,h); spreads work under both
  // linear-consecutive and mod-256 block->CU mappings.
  int u = ((blk & 15) + 5 * ((blk >> 8) & 3)) & 15;
  int qt = (u & 1) ? ((u - 1) >> 1) : (15 - (u >> 1));
  int bh = blk >> 4;
  int hh = bh & 7, b = bh >> 3;
  int t0 = qt << 6;
  int tid = threadIdx.x;
  int lane = tid & 63, w = tid >> 6;
  int lo = lane & 15, hi = lane >> 4;

  const ushort_t* qg = qkv + ((size_t)(b * TT + t0)) * 1536 + hh * 64;
  const ushort_t* kg = qkv + ((size_t)b * TT) * 1536 + 512 + hh * 64;
  const ushort_t* vg = qkv + ((size_t)b * TT) * 1536 + 1024 + hh * 64;

  // ---- stage Q once, scaled by 1/8
  for (int idx = tid; idx < 512; idx += 256) {
    int row = idx >> 3, gg = idx & 7;
    uint4 uu = *(const uint4*)(qg + (size_t)row * 1536 + gg * 8);
    unsigned int uw[4] = {uu.x, uu.y, uu.z, uu.w};
    unsigned int ow[4];
#pragma unroll
    for (int j = 0; j < 4; ++j) {
      float f0 = b2f(uw[j] & 0xffffu) * 0.125f;
      float f1 = b2f(uw[j] >> 16) * 0.125f;
      ow[j] = (unsigned int)f2b(f0) | ((unsigned int)f2b(f1) << 16);
    }
    *(uint4*)&QPs[row * 64 + ((gg ^ (row & 7)) << 3)] = make_uint4(ow[0], ow[1], ow[2], ow[3]);
  }
  __syncthreads();

  // Q A-fragments (registers); QPs rows [16w,16w+16) become wave-private P strips
  bf16x8_t faq0 = *(bf16x8_t*)&QPs[(16 * w + lo) * 64 + ((hi ^ (lo & 7)) << 3)];
  bf16x8_t faq1 = *(bf16x8_t*)&QPs[(16 * w + lo) * 64 + (((hi + 4) ^ (lo & 7)) << 3)];

  f32x4_t acc_o[4];
#pragma unroll
  for (int nd = 0; nd < 4; ++nd) acc_o[nd] = (f32x4_t){0.f, 0.f, 0.f, 0.f};
  float mrow[4] = {-1e30f, -1e30f, -1e30f, -1e30f};
  float lrow[4] = {0.f, 0.f, 0.f, 0.f};

  int nkt = (t0 >> 6) + 1;
  for (int kt = 0; kt < nkt; ++kt) {
    int k0 = kt << 6;
    __syncthreads();  // previous tile's compute done before restage
    // ---- stage K
    for (int idx = tid; idx < 512; idx += 256) {
      int row = idx >> 3, gg = idx & 7;
      uint4 uu = *(const uint4*)(kg + (size_t)(k0 + row) * 1536 + gg * 8);
      *(uint4*)&Ks[row * 64 + ((gg ^ (row & 7)) << 3)] = uu;
    }
    // ---- stage V transposed: Vt[d][kk], bank-staggered scalar stores
    for (int idx = tid; idx < 512; idx += 256) {
      int kk = idx >> 3, gd = idx & 7;
      uint4 uu = *(const uint4*)(vg + (size_t)(k0 + kk) * 1536 + gd * 8);
      unsigned int uw[4] = {uu.x, uu.y, uu.z, uu.w};
      int st = tid & 7;
#pragma unroll
      for (int ee = 0; ee < 8; ++ee) {
        int e = (ee + st) & 7;
        int eh = e >> 1;
        unsigned int word = (eh == 0) ? uw[0] : (eh == 1) ? uw[1] : (eh == 2) ? uw[2] : uw[3];
        ushort_t val = (e & 1) ? (ushort_t)(word >> 16) : (ushort_t)(word & 0xffffu);
        int d = gd * 8 + e;
        Vt[d * 64 + (((kk >> 3) ^ (d & 7)) << 3) + (kk & 7)] = val;
      }
    }
    // ---- stage rel window (rolling: 128 rows at kt=0, 64 new rows after)
    {
      const ushort_t* rbase = rel_bf + (size_t)(k0 - t0 + 961) * 64;  // 961 = R - 63
      int u0 = (kt == 0) ? 0 : 64;
      int ngr = (128 - u0) * 8;
      for (int idx = tid; idx < ngr; idx += 256) {
        int ur = u0 + (idx >> 3), gg = idx & 7;
        int phys = (ur + (kt << 6)) & 127;  // phys&7 == ur&7
        uint4 uu = *(const uint4*)(rbase + (size_t)ur * 64 + gg * 8);
        *(uint4*)&Rl[phys * 64 + ((gg ^ (ur & 7)) << 3)] = uu;
      }
    }
    __syncthreads();

    // ---- QK^T
    f32x4_t acc_s[4], acc_r[5];
#pragma unroll
    for (int nc = 0; nc < 4; ++nc) acc_s[nc] = (f32x4_t){0.f, 0.f, 0.f, 0.f};
#pragma unroll
    for (int pt = 0; pt < 5; ++pt) acc_r[pt] = (f32x4_t){0.f, 0.f, 0.f, 0.f};

#pragma unroll
    for (int nc = 0; nc < 4; ++nc) {
      int row = 16 * nc + lo;
      bf16x8_t fb0 = *(bf16x8_t*)&Ks[row * 64 + ((hi ^ (lo & 7)) << 3)];
      bf16x8_t fb1 = *(bf16x8_t*)&Ks[row * 64 + (((hi + 4) ^ (lo & 7)) << 3)];
      acc_s[nc] = __builtin_amdgcn_mfma_f32_16x16x32_bf16(faq0, fb0, acc_s[nc], 0, 0, 0);
      acc_s[nc] = __builtin_amdgcn_mfma_f32_16x16x32_bf16(faq1, fb1, acc_s[nc], 0, 0, 0);
    }
    // ---- rel window MFMAs (logical row -> rolling physical row)
#pragma unroll
    for (int pt = 0; pt < 5; ++pt) {
      int r = 16 * (3 - w + pt) + lo;
      int phys = (r + (kt << 6)) & 127;
      bf16x8_t fb0 = *(bf16x8_t*)&Rl[phys * 64 + ((hi ^ (lo & 7)) << 3)];
      bf16x8_t fb1 = *(bf16x8_t*)&Rl[phys * 64 + (((hi + 4) ^ (lo & 7)) << 3)];
      acc_r[pt] = __builtin_amdgcn_mfma_f32_16x16x32_bf16(faq0, fb0, acc_r[pt], 0, 0, 0);
      acc_r[pt] = __builtin_amdgcn_mfma_f32_16x16x32_bf16(faq1, fb1, acc_r[pt], 0, 0, 0);
    }

    bool islast = (kt == nkt - 1);
    // ---- gather rel (p = c_l - r_l + 15), mask, online softmax, P->LDS
#pragma unroll
    for (int g = 0; g < 4; ++g) {
      int rl = 4 * hi + g;
      int dd = lo + 15 - rl;
      int src = (lane & 48) | (dd & 15);
      bool carry = (dd & 16) != 0;
      float sh0 = __shfl(acc_r[0][g], src);
      float sh1 = __shfl(acc_r[1][g], src);
      float sh2 = __shfl(acc_r[2][g], src);
      float sh3 = __shfl(acc_r[3][g], src);
      float sh4 = __shfl(acc_r[4][g], src);
      float s0 = acc_s[0][g] + (carry ? sh1 : sh0);
      float s1 = acc_s[1][g] + (carry ? sh2 : sh1);
      float s2 = acc_s[2][g] + (carry ? sh3 : sh2);
      float s3 = acc_s[3][g] + (carry ? sh4 : sh3);
      if (islast) {
        int rw = 16 * w + rl;
        if (lo > rw) s0 = -1e30f;
        if (16 + lo > rw) s1 = -1e30f;
        if (32 + lo > rw) s2 = -1e30f;
        if (48 + lo > rw) s3 = -1e30f;
      }
      float mx = fmaxf(fmaxf(s0, s1), fmaxf(s2, s3));
      mx = fmaxf(mx, __shfl_xor(mx, 1));
      mx = fmaxf(mx, __shfl_xor(mx, 2));
      mx = fmaxf(mx, __shfl_xor(mx, 4));
      mx = fmaxf(mx, __shfl_xor(mx, 8));
      float mnew = fmaxf(mrow[g], mx);
      float scale = __expf(mrow[g] - mnew);
      mrow[g] = mnew;
      float p0 = __expf(s0 - mnew);
      float p1 = __expf(s1 - mnew);
      float p2 = __expf(s2 - mnew);
      float p3 = __expf(s3 - mnew);
      float ls = p0 + p1 + p2 + p3;
      ls += __shfl_xor(ls, 1);
      ls += __shfl_xor(ls, 2);
      ls += __shfl_xor(ls, 4);
      ls += __shfl_xor(ls, 8);
      lrow[g] = lrow[g] * scale + ls;
      acc_o[0][g] *= scale; acc_o[1][g] *= scale;
      acc_o[2][g] *= scale; acc_o[3][g] *= scale;
      ushort_t* pr = &QPs[(16 * w + rl) * 64];  // wave-private strip
      int rsw = rl & 7, l3 = lo >> 3, l7 = lo & 7;
      pr[(((0 + l3) ^ rsw) << 3) + l7] = f2b(p0);
      pr[(((2 + l3) ^ rsw) << 3) + l7] = f2b(p1);
      pr[(((4 + l3) ^ rsw) << 3) + l7] = f2b(p2);
      pr[(((6 + l3) ^ rsw) << 3) + l7] = f2b(p3);
    }

    // ---- PV
    bf16x8_t pa0 = *(bf16x8_t*)&QPs[(16 * w + lo) * 64 + ((hi ^ (lo & 7)) << 3)];
    bf16x8_t pa1 = *(bf16x8_t*)&QPs[(16 * w + lo) * 64 + (((hi + 4) ^ (lo & 7)) << 3)];
#pragma unroll
    for (int nd = 0; nd < 4; ++nd) {
      int row = 16 * nd + lo;
      bf16x8_t fb0 = *(bf16x8_t*)&Vt[row * 64 + ((hi ^ (lo & 7)) << 3)];
      bf16x8_t fb1 = *(bf16x8_t*)&Vt[row * 64 + (((hi + 4) ^ (lo & 7)) << 3)];
      acc_o[nd] = __builtin_amdgcn_mfma_f32_16x16x32_bf16(pa0, fb0, acc_o[nd], 0, 0, 0);
      acc_o[nd] = __builtin_amdgcn_mfma_f32_16x16x32_bf16(pa1, fb1, acc_o[nd], 0, 0, 0);
    }
  }

  // ---- output
  ushort_t* og = o + ((size_t)(b * TT + t0 + 16 * w)) * D_ + hh * HD_;
#pragma unroll
  for (int g = 0; g < 4; ++g) {
    int rl = 4 * hi + g;
    float inv = 1.0f / lrow[g];
#pragma unroll
    for (int nd = 0; nd < 4; ++nd)
      og[(size_t)rl * D_ + 16 * nd + lo] = f2b(acc_o[nd][g] * inv);
  }
}

// ---------------------------------------------------------------- residual + layernorm (f32 h in-place, bf16 copy)
__global__ __launch_bounds__(256) void ln_res_kernel(float* __restrict__ h,
                                                     const float* __restrict__ y,
                                                     const float* __restrict__ s,
                                                     const float* __restrict__ bvec,
                                                     ushort_t* __restrict__ h_bf) {
  int row = blockIdx.x;
  int tid = threadIdx.x;
  size_t base = (size_t)row * D_;
  float z0 = h[base + tid] + y[base + tid];
  float z1 = h[base + tid + 256] + y[base + tid + 256];
  __shared__ float r1[256], r2[256];
  r1[tid] = z0 + z1;
  r2[tid] = z0 * z0 + z1 * z1;
  __syncthreads();
  for (int off = 128; off > 0; off >>= 1) {
    if (tid < off) {
      r1[tid] += r1[tid + off];
      r2[tid] += r2[tid + off];
    }
    __syncthreads();
  }
  float mu = r1[0] * (1.0f / 512.0f);
  float var = r2[0] * (1.0f / 512.0f) - mu * mu;
  float rs = rsqrtf(var + 1e-5f);
  float o0 = (z0 - mu) * rs * s[tid] + bvec[tid];
  float o1 = (z1 - mu) * rs * s[tid + 256] + bvec[tid + 256];
  h[base + tid] = o0;
  h[base + tid + 256] = o1;
  h_bf[base + tid] = f2b(o0);
  h_bf[base + tid + 256] = f2b(o1);
}

// ---------------------------------------------------------------- chord gather (f32)
__global__ void gather_kernel(const float* __restrict__ h, const int* __restrict__ pos,
                              float* __restrict__ g) {
  int row = blockIdx.x;
  int b = row >> 7;
  int p = pos[row];
  if (p < 0) p = 0;
  size_t src = ((size_t)(b * TT + p)) * D_;
  size_t dst = (size_t)row * D_;
  for (int d = threadIdx.x; d < D_; d += 256) g[dst + d] = h[src + d];
}

// ---------------------------------------------------------------- launcher
extern "C" void kernel_launch(void* const* d_in, const int* in_sizes, int n_in,
                              void* d_out, int out_size, void* d_ws, size_t ws_size,
                              hipStream_t stream) {
  const int* x = (const int*)d_in[0];
  const int* cpos = (const int*)d_in[1];
  const float* emb = (const float*)d_in[2];
  const float* rel = (const float*)d_in[3];
  const float* Wq = (const float*)d_in[4];
  const float* bq = (const float*)d_in[5];
  const float* Wk = (const float*)d_in[6];
  const float* bk = (const float*)d_in[7];
  const float* Wv = (const float*)d_in[8];
  const float* bv = (const float*)d_in[9];
  const float* Wo = (const float*)d_in[10];
  const float* bo = (const float*)d_in[11];
  const float* ln1s = (const float*)d_in[12];
  const float* ln1b = (const float*)d_in[13];
  const float* W1 = (const float*)d_in[14];
  const float* b1 = (const float*)d_in[15];
  const float* W2 = (const float*)d_in[16];
  const float* b2 = (const float*)d_in[17];
  const float* ln2s = (const float*)d_in[18];
  const float* ln2b = (const float*)d_in[19];
  const float* Wout = (const float*)d_in[20];
  const float* bout = (const float*)d_in[21];
  const float* Wc = (const float*)d_in[22];
  const float* bc = (const float*)d_in[23];

  const size_t SZ = (size_t)BT_ * D_;  // 4M elems
  const size_t WPROJ = (size_t)D_ * D_;
  const size_t WFFN = (size_t)D_ * F_;

  float* h = (float*)d_ws;
  float* y = h + SZ;
  ushort_t* h_bf = (ushort_t*)(y + SZ);
  ushort_t* qkv_bf = h_bf + SZ;                       // BT*1536
  ushort_t* o_bf = qkv_bf + (size_t)BT_ * 1536;
  ushort_t* mid_bf = o_bf + SZ;                       // BT*F
  ushort_t* wqkvT = mid_bf + (size_t)BT_ * F_;        // 12*1536*512
  ushort_t* woT = wqkvT + (size_t)L_ * 1536 * 512;
  ushort_t* w1T = woT + L_ * WPROJ;
  ushort_t* w2T = w1T + L_ * WFFN;
  ushort_t* woutT = w2T + L_ * WFFN;
  ushort_t* wcT = woutT + (size_t)D_ * V_;
  ushort_t* rel_bf = wcT + (size_t)D_ * C_;           // L*NR*64
  float* bqkv = (float*)(rel_bf + (size_t)L_ * NR_ * HD_);
  float* gath = bqkv + L_ * 1536;
  float* out = (float*)d_out;

  // ---- pre-pass: weights/bias/rel to bf16 layouts
  for (int l = 0; l < L_; ++l) {
    transpose_bf16<<<dim3(D_ / 32, D_ / 32), 256, 0, stream>>>(
        Wq + (size_t)l * WPROJ, wqkvT + ((size_t)l * 1536 + 0) * 512, D_, D_);
    transpose_bf16<<<dim3(D_ / 32, D_ / 32), 256, 0, stream>>>(
        Wk + (size_t)l * WPROJ, wqkvT + ((size_t)l * 1536 + 512) * 512, D_, D_);
    transpose_bf16<<<dim3(D_ / 32, D_ / 32), 256, 0, stream>>>(
        Wv + (size_t)l * WPROJ, wqkvT + ((size_t)l * 1536 + 1024) * 512, D_, D_);
    transpose_bf16<<<dim3(D_ / 32, D_ / 32), 256, 0, stream>>>(
        Wo + (size_t)l * WPROJ, woT + l * WPROJ, D_, D_);
    transpose_bf16<<<dim3(F_ / 32, D_ / 32), 256, 0, stream>>>(
        W1 + (size_t)l * WFFN, w1T + l * WFFN, D_, F_);
    transpose_bf16<<<dim3(D_ / 32, F_ / 32), 256, 0, stream>>>(
        W2 + (size_t)l * WFFN, w2T + l * WFFN, F_, D_);
  }
  transpose_bf16<<<dim3(V_ / 32, D_ / 32), 256, 0, stream>>>(Wout, woutT, D_, V_);
  transpose_bf16<<<dim3(C_ / 32, D_ / 32), 256, 0, stream>>>(Wc, wcT, D_, C_);
  rel_convert<<<1537, 256, 0, stream>>>(rel, rel_bf);
  pack_bias<<<(L_ * 1536 + 255) / 256, 256, 0, stream>>>(bq, bk, bv, bqkv);

  embed_kernel<<<BT_, 256, 0, stream>>>(x, emb, h, h_bf);

  dim3 gQKV(1536 / 128, BT_ / 128);  // (12,64)
  dim3 gProj(D_ / 128, BT_ / 128);   // (4,64)
  dim3 gF1(F_ / 128, BT_ / 128);     // (16,64)
  dim3 gOut(V_ / 128, BT_ / 128);    // (16,64)

  for (int l = 0; l < L_; ++l) {
    gemm_mfma<1, 0><<<gQKV, 256, 0, stream>>>(h_bf, wqkvT + (size_t)l * 1536 * 512,
                                              bqkv + l * 1536, qkv_bf, BT_, 1536, D_);
    attn_mfma<<<B_ * H_ * (TT / 64), 256, 0, stream>>>(qkv_bf, rel_bf + (size_t)l * NR_ * HD_, o_bf);
    gemm_mfma<0, 0><<<gProj, 256, 0, stream>>>(o_bf, woT + l * WPROJ, bo + l * D_, y, BT_, D_, D_);
    ln_res_kernel<<<BT_, 256, 0, stream>>>(h, y, ln1s + l * D_, ln1b + l * D_, h_bf);
    gemm_mfma<1, 1><<<gF1, 256, 0, stream>>>(h_bf, w1T + l * WFFN, b1 + l * F_, mid_bf, BT_, F_, D_);
    gemm_mfma<0, 0><<<gProj, 256, 0, stream>>>(mid_bf, w2T + l * WFFN, b2 + l * D_, y, BT_, D_, F_);
    ln_res_kernel<<<BT_, 256, 0, stream>>>(h, y, ln2s + l * D_, ln2b + l * D_, h_bf);
  }

  gemm_mfma<0, 0><<<gOut, 256, 0, stream>>>(h_bf, woutT, bout, out, BT_, V_, D_);
  gather_kernel<<<B_ * M_, 256, 0, stream>>>(h, cpos, gath);
  gemm_bias<0><<<dim3(1, (B_ * M_) / 64), 256, 0, stream>>>(gath, Wc, bc, out + (size_t)BT_ * V_,
                                                            B_ * M_, C_, D_);
}

// Round 8
// 2542.171 us; speedup vs baseline: 21.2358x; 1.2509x over previous
//
#include <hip/hip_runtime.h>
#include <hip/hip_bf16.h>
#include <cstddef>

constexpr int B_ = 8, TT = 1024, H_ = 8, HD_ = 64, D_ = 512, F_ = 2048;
constexpr int L_ = 12, R_ = 1024, NR_ = 2049, C_ = 64, M_ = 128, V_ = 2048;
constexpr int BT_ = B_ * TT;  // 8192

typedef short bf16x8_t __attribute__((ext_vector_type(8)));
typedef float f32x4_t __attribute__((ext_vector_type(4)));
typedef unsigned short ushort_t;

__device__ __forceinline__ float b2f(unsigned int u16) {
  return __uint_as_float(u16 << 16);
}
__device__ __forceinline__ ushort_t f2b(float f) {
  __hip_bfloat16 h = __float2bfloat16(f);
  return *reinterpret_cast<ushort_t*>(&h);
}

// ---------------------------------------------------------------- batched weight transpose: src (K,N) f32 -> dst (N,K) bf16
__global__ __launch_bounds__(256) void transpose_bf16_b(const float* __restrict__ src,
                                                        ushort_t* __restrict__ dst,
                                                        int K, int N,
                                                        size_t sstride, size_t dstride) {
  __shared__ float t[32][33];
  src += (size_t)blockIdx.z * sstride;
  dst += (size_t)blockIdx.z * dstride;
  int k0 = blockIdx.y * 32, n0 = blockIdx.x * 32;
  int r = threadIdx.x >> 3, c4 = (threadIdx.x & 7) * 4;
  float4 vv = *(const float4*)(src + (size_t)(k0 + r) * N + n0 + c4);
  t[r][c4] = vv.x; t[r][c4 + 1] = vv.y; t[r][c4 + 2] = vv.z; t[r][c4 + 3] = vv.w;
  __syncthreads();
  ushort4 w;
  w.x = f2b(t[c4 + 0][r]); w.y = f2b(t[c4 + 1][r]);
  w.z = f2b(t[c4 + 2][r]); w.w = f2b(t[c4 + 3][r]);
  *(ushort4*)(dst + (size_t)(n0 + r) * K + k0 + c4) = w;
}

// ---------------------------------------------------------------- rel f32 -> bf16 (all layers)
__global__ __launch_bounds__(256) void rel_convert(const float* __restrict__ rel,
                                                   ushort_t* __restrict__ rel_bf) {
  size_t idx = ((size_t)blockIdx.x * 256 + threadIdx.x) * 4;
  const size_t total = (size_t)L_ * NR_ * HD_;
  if (idx >= total) return;
  float4 f = *(const float4*)(rel + idx);
  ushort4 w;
  w.x = f2b(f.x); w.y = f2b(f.y); w.z = f2b(f.z); w.w = f2b(f.w);
  *(ushort4*)(rel_bf + idx) = w;
}

// ---------------------------------------------------------------- pack q/k/v biases -> bqkv[l][1536]
__global__ __launch_bounds__(256) void pack_bias(const float* __restrict__ bq,
                                                 const float* __restrict__ bk,
                                                 const float* __restrict__ bv,
                                                 float* __restrict__ bqkv) {
  int idx = blockIdx.x * 256 + threadIdx.x;
  if (idx >= L_ * 1536) return;
  int l = idx / 1536, c = idx - l * 1536;
  float v;
  if (c < 512) v = bq[l * 512 + c];
  else if (c < 1024) v = bk[l * 512 + (c - 512)];
  else v = bv[l * 512 + (c - 1024)];
  bqkv[idx] = v;
}

// ---------------------------------------------------------------- embedding + posenc (f32 + bf16 out)
__global__ void embed_kernel(const int* __restrict__ x, const float* __restrict__ emb,
                             float* __restrict__ h, ushort_t* __restrict__ h_bf) {
  int bt = blockIdx.x;
  int t = bt & (TT - 1);
  int tok = x[bt];
  const float c = -9.210340371976184f / 512.0f;
  size_t base = (size_t)bt * D_;
  size_t ebase = (size_t)tok * D_;
  for (int d = threadIdx.x; d < D_; d += 256) {
    int i = d >> 1;
    float div = expf((float)(2 * i) * c);
    float arg = (float)t * div;
    float pe = (d & 1) ? cosf(arg) : sinf(arg);
    float vv = emb[ebase + d] * 22.627416997969522f + pe;
    h[base + d] = vv;
    h_bf[base + d] = f2b(vv);
  }
}

// ---------------------------------------------------------------- MFMA GEMM: C = A@B + bias
template <int OUT_BF16, int RELU>
__global__ __launch_bounds__(256) void gemm_mfma(const ushort_t* __restrict__ A,
                                                 const ushort_t* __restrict__ Bt,
                                                 const float* __restrict__ bias,
                                                 void* __restrict__ Cout,
                                                 int Mm, int N, int K) {
  __shared__ ushort_t As[128 * 32];
  __shared__ ushort_t Bs[128 * 32];
  int tid = threadIdx.x;
  int m0 = blockIdx.y * 128, n0 = blockIdx.x * 128;
  int lane = tid & 63, wid = tid >> 6;
  int wr = wid >> 1, wc = wid & 1;

  f32x4_t acc[4][4];
#pragma unroll
  for (int mi = 0; mi < 4; ++mi)
#pragma unroll
    for (int ni = 0; ni < 4; ++ni) acc[mi][ni] = (f32x4_t){0.f, 0.f, 0.f, 0.f};

  int c0 = tid, c1 = tid + 256;
  int ar0 = c0 >> 2, ap0 = c0 & 3, akg0 = ap0 ^ ((ar0 >> 1) & 3);
  int ar1 = c1 >> 2, ap1 = c1 & 3, akg1 = ap1 ^ ((ar1 >> 1) & 3);
  const ushort_t* Arow0 = A + (size_t)(m0 + ar0) * K + akg0 * 8;
  const ushort_t* Arow1 = A + (size_t)(m0 + ar1) * K + akg1 * 8;
  const ushort_t* Brow0 = Bt + (size_t)(n0 + ar0) * K + akg0 * 8;
  const ushort_t* Brow1 = Bt + (size_t)(n0 + ar1) * K + akg1 * 8;

  uint4 ra0 = *(const uint4*)(Arow0);
  uint4 ra1 = *(const uint4*)(Arow1);
  uint4 rb0 = *(const uint4*)(Brow0);
  uint4 rb1 = *(const uint4*)(Brow1);

  int NT = K >> 5;
  int kg = lane >> 4, rl = lane & 15;
  for (int kt = 0; kt < NT; ++kt) {
    __syncthreads();
    *(uint4*)&As[ar0 * 32 + ap0 * 8] = ra0;
    *(uint4*)&As[ar1 * 32 + ap1 * 8] = ra1;
    *(uint4*)&Bs[ar0 * 32 + ap0 * 8] = rb0;
    *(uint4*)&Bs[ar1 * 32 + ap1 * 8] = rb1;
    __syncthreads();
    if (kt + 1 < NT) {
      int ko = (kt + 1) << 5;
      ra0 = *(const uint4*)(Arow0 + ko);
      ra1 = *(const uint4*)(Arow1 + ko);
      rb0 = *(const uint4*)(Brow0 + ko);
      rb1 = *(const uint4*)(Brow1 + ko);
    }
    bf16x8_t fa[4], fb[4];
#pragma unroll
    for (int mi = 0; mi < 4; ++mi) {
      int r = wr * 64 + mi * 16 + rl;
      fa[mi] = *(bf16x8_t*)&As[r * 32 + ((kg ^ ((r >> 1) & 3)) << 3)];
    }
#pragma unroll
    for (int ni = 0; ni < 4; ++ni) {
      int r = wc * 64 + ni * 16 + rl;
      fb[ni] = *(bf16x8_t*)&Bs[r * 32 + ((kg ^ ((r >> 1) & 3)) << 3)];
    }
#pragma unroll
    for (int mi = 0; mi < 4; ++mi)
#pragma unroll
      for (int ni = 0; ni < 4; ++ni)
        acc[mi][ni] = __builtin_amdgcn_mfma_f32_16x16x32_bf16(fa[mi], fb[ni], acc[mi][ni], 0, 0, 0);
  }

  int rg = lane >> 4;
#pragma unroll
  for (int ni = 0; ni < 4; ++ni) {
    int col = n0 + wc * 64 + ni * 16 + rl;
    float bv = bias[col];
#pragma unroll
    for (int mi = 0; mi < 4; ++mi) {
      int row0 = m0 + wr * 64 + mi * 16 + rg * 4;
#pragma unroll
      for (int r = 0; r < 4; ++r) {
        float vv = acc[mi][ni][r] + bv;
        if (RELU) vv = fmaxf(vv, 0.0f);
        if (OUT_BF16)
          ((ushort_t*)Cout)[(size_t)(row0 + r) * N + col] = f2b(vv);
        else
          ((float*)Cout)[(size_t)(row0 + r) * N + col] = vv;
      }
    }
  }
}

// ---------------------------------------------------------------- legacy f32 GEMM (chord head only)
template <int RELU>
__global__ __launch_bounds__(256) void gemm_bias(const float* __restrict__ A,
                                                 const float* __restrict__ W,
                                                 const float* __restrict__ bias,
                                                 float* __restrict__ Cm,
                                                 int Mm, int N, int K) {
  __shared__ float As[64][17];
  __shared__ float Bs[16][65];
  int tid = threadIdx.x;
  int tx = tid & 15, ty = tid >> 4;
  int row0 = blockIdx.y * 64, col0 = blockIdx.x * 64;
  float acc[4][4] = {};
  int ra = tid >> 4, ca = tid & 15;
  int rb = tid >> 6, cb = tid & 63;
  for (int k0 = 0; k0 < K; k0 += 16) {
    for (int rr = ra; rr < 64; rr += 16)
      As[rr][ca] = A[(size_t)(row0 + rr) * K + k0 + ca];
    for (int rr = rb; rr < 16; rr += 4)
      Bs[rr][cb] = W[(size_t)(k0 + rr) * N + col0 + cb];
    __syncthreads();
#pragma unroll
    for (int kk = 0; kk < 16; ++kk) {
      float a[4], bb[4];
#pragma unroll
      for (int i = 0; i < 4; ++i) a[i] = As[ty * 4 + i][kk];
#pragma unroll
      for (int j = 0; j < 4; ++j) bb[j] = Bs[kk][tx * 4 + j];
#pragma unroll
      for (int i = 0; i < 4; ++i)
#pragma unroll
        for (int j = 0; j < 4; ++j) acc[i][j] += a[i] * bb[j];
    }
    __syncthreads();
  }
#pragma unroll
  for (int i = 0; i < 4; ++i) {
#pragma unroll
    for (int j = 0; j < 4; ++j) {
      float vv = acc[i][j] + bias[col0 + tx * 4 + j];
      if (RELU) vv = fmaxf(vv, 0.0f);
      Cm[(size_t)(row0 + ty * 4 + i) * N + col0 + tx * 4 + j] = vv;
    }
  }
}

// ---------------------------------------------------------------- MFMA causal attention with fused rel-pos
// Block: 64 q-rows of one (b,h), 4 waves x 16 rows. K-tiles of 64.
// Reg-prefetched staging; V staged subtiled [kb][db][4][16] and read via
// ds_read_b64_tr_b16 (per-lane gather: region=addr&~127, col=(addr>>3)&15).
__global__ __launch_bounds__(256) void attn_mfma(const ushort_t* __restrict__ qkv,
                                                 const ushort_t* __restrict__ rel_bf,
                                                 ushort_t* __restrict__ o) {
  __shared__ ushort_t QPs[64 * 64];  // 8 KB: Q in prologue, P strips in loop
  __shared__ ushort_t Ks[64 * 64];   // 8 KB
  __shared__ ushort_t Vs[64 * 64];   // 8 KB subtiled [kb][db][4][16]
  __shared__ ushort_t Rl[128 * 64];  // 16 KB rolling rel window

  int blk = blockIdx.x;
  int u = ((blk & 15) + 5 * ((blk >> 8) & 3)) & 15;
  int qt = (u & 1) ? ((u - 1) >> 1) : (15 - (u >> 1));
  int bh = blk >> 4;
  int hh = bh & 7, b = bh >> 3;
  int t0 = qt << 6;
  int tid = threadIdx.x;
  int lane = tid & 63, w = tid >> 6;
  int lo = lane & 15, hi = lane >> 4;

  const ushort_t* qg = qkv + ((size_t)(b * TT + t0)) * 1536 + hh * 64;
  const ushort_t* kg = qkv + ((size_t)b * TT) * 1536 + 512 + hh * 64;
  const ushort_t* vg = qkv + ((size_t)b * TT) * 1536 + 1024 + hh * 64;
  const ushort_t* relb = rel_bf + (size_t)(961 - t0) * 64;  // 961 = R - 63

  int row_a = tid >> 3, gg_a = tid & 7;  // chunk A rows 0..31; chunk B +32
  int row_b = row_a + 32;

  // ---- stage Q once, scaled by 1/8
  for (int idx = tid; idx < 512; idx += 256) {
    int row = idx >> 3, gg = idx & 7;
    uint4 uu = *(const uint4*)(qg + (size_t)row * 1536 + gg * 8);
    unsigned int uw[4] = {uu.x, uu.y, uu.z, uu.w};
    unsigned int ow[4];
#pragma unroll
    for (int j = 0; j < 4; ++j) {
      float f0 = b2f(uw[j] & 0xffffu) * 0.125f;
      float f1 = b2f(uw[j] >> 16) * 0.125f;
      ow[j] = (unsigned int)f2b(f0) | ((unsigned int)f2b(f1) << 16);
    }
    *(uint4*)&QPs[row * 64 + ((gg ^ (row & 7)) << 3)] = make_uint4(ow[0], ow[1], ow[2], ow[3]);
  }
  __syncthreads();

  bf16x8_t faq0 = *(bf16x8_t*)&QPs[(16 * w + lo) * 64 + ((hi ^ (lo & 7)) << 3)];
  bf16x8_t faq1 = *(bf16x8_t*)&QPs[(16 * w + lo) * 64 + (((hi + 4) ^ (lo & 7)) << 3)];

  // ---- prologue prefetch (tile 0)
  uint4 pk0 = *(const uint4*)(kg + (size_t)row_a * 1536 + gg_a * 8);
  uint4 pk1 = *(const uint4*)(kg + (size_t)row_b * 1536 + gg_a * 8);
  uint4 pv0 = *(const uint4*)(vg + (size_t)row_a * 1536 + gg_a * 8);
  uint4 pv1 = *(const uint4*)(vg + (size_t)row_b * 1536 + gg_a * 8);
  uint4 pr0 = *(const uint4*)(relb + (size_t)row_a * 64 + gg_a * 8);
  uint4 pr1 = *(const uint4*)(relb + (size_t)(row_a + 32) * 64 + gg_a * 8);
  uint4 pr2 = *(const uint4*)(relb + (size_t)(row_a + 64) * 64 + gg_a * 8);
  uint4 pr3 = *(const uint4*)(relb + (size_t)(row_a + 96) * 64 + gg_a * 8);

  f32x4_t acc_o[4];
#pragma unroll
  for (int nd = 0; nd < 4; ++nd) acc_o[nd] = (f32x4_t){0.f, 0.f, 0.f, 0.f};
  float mrow[4] = {-1e30f, -1e30f, -1e30f, -1e30f};
  float lrow[4] = {0.f, 0.f, 0.f, 0.f};

  int vsb = (int)(size_t)(const void*)Vs;  // LDS byte offset (flat low bits)
  int tb0 = vsb + ((2 * hi + 0) * 4) * 128 + lo * 8;
  int tb1 = vsb + ((2 * hi + 1) * 4) * 128 + lo * 8;
  int tb2 = vsb + ((2 * hi + 8) * 4) * 128 + lo * 8;
  int tb3 = vsb + ((2 * hi + 9) * 4) * 128 + lo * 8;

  int nkt = (t0 >> 6) + 1;
  for (int kt = 0; kt < nkt; ++kt) {
    __syncthreads();  // previous compute done; LDS free
    // ---- store staged regs to LDS
    *(uint4*)&Ks[row_a * 64 + ((gg_a ^ (row_a & 7)) << 3)] = pk0;
    *(uint4*)&Ks[row_b * 64 + ((gg_a ^ (row_b & 7)) << 3)] = pk1;
    *(uint4*)&Vs[((row_a >> 2) * 4 + (gg_a >> 1)) * 64 + (row_a & 3) * 16 + (gg_a & 1) * 8] = pv0;
    *(uint4*)&Vs[((row_b >> 2) * 4 + (gg_a >> 1)) * 64 + (row_b & 3) * 16 + (gg_a & 1) * 8] = pv1;
    if (kt == 0) {
      int u0 = row_a;
      *(uint4*)&Rl[u0 * 64 + ((gg_a ^ (u0 & 7)) << 3)] = pr0;
      int u1 = row_a + 32;
      *(uint4*)&Rl[u1 * 64 + ((gg_a ^ (u1 & 7)) << 3)] = pr1;
      int u2 = row_a + 64;
      *(uint4*)&Rl[u2 * 64 + ((gg_a ^ (u2 & 7)) << 3)] = pr2;
      int u3 = row_a + 96;
      *(uint4*)&Rl[u3 * 64 + ((gg_a ^ (u3 & 7)) << 3)] = pr3;
    } else {
      int ur0 = 64 + row_a, ph0 = (ur0 + (kt << 6)) & 127;
      *(uint4*)&Rl[ph0 * 64 + ((gg_a ^ (ur0 & 7)) << 3)] = pr0;
      int ur1 = 64 + row_b, ph1 = (ur1 + (kt << 6)) & 127;
      *(uint4*)&Rl[ph1 * 64 + ((gg_a ^ (ur1 & 7)) << 3)] = pr1;
    }
    __syncthreads();
    // ---- prefetch next tile into regs (overlaps with compute below)
    if (kt + 1 < nkt) {
      size_t ko = (size_t)((kt + 1) << 6);
      pk0 = *(const uint4*)(kg + (ko + row_a) * 1536 + gg_a * 8);
      pk1 = *(const uint4*)(kg + (ko + row_b) * 1536 + gg_a * 8);
      pv0 = *(const uint4*)(vg + (ko + row_a) * 1536 + gg_a * 8);
      pv1 = *(const uint4*)(vg + (ko + row_b) * 1536 + gg_a * 8);
      pr0 = *(const uint4*)(relb + (ko + 64 + row_a) * 64 + gg_a * 8);
      pr1 = *(const uint4*)(relb + (ko + 64 + row_b) * 64 + gg_a * 8);
    }

    // ---- QK^T + rel MFMAs
    f32x4_t acc_s[4], acc_r[5];
#pragma unroll
    for (int nc = 0; nc < 4; ++nc) acc_s[nc] = (f32x4_t){0.f, 0.f, 0.f, 0.f};
#pragma unroll
    for (int pt = 0; pt < 5; ++pt) acc_r[pt] = (f32x4_t){0.f, 0.f, 0.f, 0.f};

    __builtin_amdgcn_s_setprio(1);
#pragma unroll
    for (int nc = 0; nc < 4; ++nc) {
      int row = 16 * nc + lo;
      bf16x8_t fb0 = *(bf16x8_t*)&Ks[row * 64 + ((hi ^ (lo & 7)) << 3)];
      bf16x8_t fb1 = *(bf16x8_t*)&Ks[row * 64 + (((hi + 4) ^ (lo & 7)) << 3)];
      acc_s[nc] = __builtin_amdgcn_mfma_f32_16x16x32_bf16(faq0, fb0, acc_s[nc], 0, 0, 0);
      acc_s[nc] = __builtin_amdgcn_mfma_f32_16x16x32_bf16(faq1, fb1, acc_s[nc], 0, 0, 0);
    }
#pragma unroll
    for (int pt = 0; pt < 5; ++pt) {
      int r = 16 * (3 - w + pt) + lo;
      int phys = (r + (kt << 6)) & 127;
      bf16x8_t fb0 = *(bf16x8_t*)&Rl[phys * 64 + ((hi ^ (lo & 7)) << 3)];
      bf16x8_t fb1 = *(bf16x8_t*)&Rl[phys * 64 + (((hi + 4) ^ (lo & 7)) << 3)];
      acc_r[pt] = __builtin_amdgcn_mfma_f32_16x16x32_bf16(faq0, fb0, acc_r[pt], 0, 0, 0);
      acc_r[pt] = __builtin_amdgcn_mfma_f32_16x16x32_bf16(faq1, fb1, acc_r[pt], 0, 0, 0);
    }
    __builtin_amdgcn_s_setprio(0);

    bool islast = (kt == nkt - 1);
    // ---- gather rel (p = c_l - r_l + 15), mask, online softmax, P->LDS
#pragma unroll
    for (int g = 0; g < 4; ++g) {
      int rl = 4 * hi + g;
      int dd = lo + 15 - rl;
      int src = (lane & 48) | (dd & 15);
      bool carry = (dd & 16) != 0;
      float sh0 = __shfl(acc_r[0][g], src);
      float sh1 = __shfl(acc_r[1][g], src);
      float sh2 = __shfl(acc_r[2][g], src);
      float sh3 = __shfl(acc_r[3][g], src);
      float sh4 = __shfl(acc_r[4][g], src);
      float s0 = acc_s[0][g] + (carry ? sh1 : sh0);
      float s1 = acc_s[1][g] + (carry ? sh2 : sh1);
      float s2 = acc_s[2][g] + (carry ? sh3 : sh2);
      float s3 = acc_s[3][g] + (carry ? sh4 : sh3);
      if (islast) {
        int rw = 16 * w + rl;
        if (lo > rw) s0 = -1e30f;
        if (16 + lo > rw) s1 = -1e30f;
        if (32 + lo > rw) s2 = -1e30f;
        if (48 + lo > rw) s3 = -1e30f;
      }
      float mx = fmaxf(fmaxf(s0, s1), fmaxf(s2, s3));
      mx = fmaxf(mx, __shfl_xor(mx, 1));
      mx = fmaxf(mx, __shfl_xor(mx, 2));
      mx = fmaxf(mx, __shfl_xor(mx, 4));
      mx = fmaxf(mx, __shfl_xor(mx, 8));
      float mnew = fmaxf(mrow[g], mx);
      float scale = __expf(mrow[g] - mnew);
      mrow[g] = mnew;
      float p0 = __expf(s0 - mnew);
      float p1 = __expf(s1 - mnew);
      float p2 = __expf(s2 - mnew);
      float p3 = __expf(s3 - mnew);
      float ls = p0 + p1 + p2 + p3;
      ls += __shfl_xor(ls, 1);
      ls += __shfl_xor(ls, 2);
      ls += __shfl_xor(ls, 4);
      ls += __shfl_xor(ls, 8);
      lrow[g] = lrow[g] * scale + ls;
      acc_o[0][g] *= scale; acc_o[1][g] *= scale;
      acc_o[2][g] *= scale; acc_o[3][g] *= scale;
      ushort_t* pr = &QPs[(16 * w + rl) * 64];
      int rsw = rl & 7, l3 = lo >> 3, l7 = lo & 7;
      pr[(((0 + l3) ^ rsw) << 3) + l7] = f2b(p0);
      pr[(((2 + l3) ^ rsw) << 3) + l7] = f2b(p1);
      pr[(((4 + l3) ^ rsw) << 3) + l7] = f2b(p2);
      pr[(((6 + l3) ^ rsw) << 3) + l7] = f2b(p3);
    }

    // ---- PV: P fragments + V^T via hardware transpose-read
    bf16x8_t pa0 = *(bf16x8_t*)&QPs[(16 * w + lo) * 64 + ((hi ^ (lo & 7)) << 3)];
    bf16x8_t pa1 = *(bf16x8_t*)&QPs[(16 * w + lo) * 64 + (((hi + 4) ^ (lo & 7)) << 3)];
    unsigned long long tr0[4], tr1[4], tr2[4], tr3[4];
#pragma unroll
    for (int nd = 0; nd < 4; ++nd) {
      asm volatile("ds_read_b64_tr_b16 %0, %1" : "=v"(tr0[nd]) : "v"(tb0 + nd * 128));
      asm volatile("ds_read_b64_tr_b16 %0, %1" : "=v"(tr1[nd]) : "v"(tb1 + nd * 128));
      asm volatile("ds_read_b64_tr_b16 %0, %1" : "=v"(tr2[nd]) : "v"(tb2 + nd * 128));
      asm volatile("ds_read_b64_tr_b16 %0, %1" : "=v"(tr3[nd]) : "v"(tb3 + nd * 128));
    }
    asm volatile("s_waitcnt lgkmcnt(0)" ::: "memory");
    __builtin_amdgcn_sched_barrier(0);
    __builtin_amdgcn_s_setprio(1);
#pragma unroll
    for (int nd = 0; nd < 4; ++nd) {
      union { unsigned long long u[2]; bf16x8_t v; } cv0, cv1;
      cv0.u[0] = tr0[nd]; cv0.u[1] = tr1[nd];
      cv1.u[0] = tr2[nd]; cv1.u[1] = tr3[nd];
      acc_o[nd] = __builtin_amdgcn_mfma_f32_16x16x32_bf16(pa0, cv0.v, acc_o[nd], 0, 0, 0);
      acc_o[nd] = __builtin_amdgcn_mfma_f32_16x16x32_bf16(pa1, cv1.v, acc_o[nd], 0, 0, 0);
    }
    __builtin_amdgcn_s_setprio(0);
  }

  // ---- output
  ushort_t* og = o + ((size_t)(b * TT + t0 + 16 * w)) * D_ + hh * HD_;
#pragma unroll
  for (int g = 0; g < 4; ++g) {
    int rl = 4 * hi + g;
    float inv = 1.0f / lrow[g];
#pragma unroll
    for (int nd = 0; nd < 4; ++nd)
      og[(size_t)rl * D_ + 16 * nd + lo] = f2b(acc_o[nd][g] * inv);
  }
}

// ---------------------------------------------------------------- residual + layernorm (f32 h in-place, bf16 copy)
__global__ __launch_bounds__(256) void ln_res_kernel(float* __restrict__ h,
                                                     const float* __restrict__ y,
                                                     const float* __restrict__ s,
                                                     const float* __restrict__ bvec,
                                                     ushort_t* __restrict__ h_bf) {
  int row = blockIdx.x;
  int tid = threadIdx.x;
  size_t base = (size_t)row * D_;
  float z0 = h[base + tid] + y[base + tid];
  float z1 = h[base + tid + 256] + y[base + tid + 256];
  __shared__ float r1[256], r2[256];
  r1[tid] = z0 + z1;
  r2[tid] = z0 * z0 + z1 * z1;
  __syncthreads();
  for (int off = 128; off > 0; off >>= 1) {
    if (tid < off) {
      r1[tid] += r1[tid + off];
      r2[tid] += r2[tid + off];
    }
    __syncthreads();
  }
  float mu = r1[0] * (1.0f / 512.0f);
  float var = r2[0] * (1.0f / 512.0f) - mu * mu;
  float rs = rsqrtf(var + 1e-5f);
  float o0 = (z0 - mu) * rs * s[tid] + bvec[tid];
  float o1 = (z1 - mu) * rs * s[tid + 256] + bvec[tid + 256];
  h[base + tid] = o0;
  h[base + tid + 256] = o1;
  h_bf[base + tid] = f2b(o0);
  h_bf[base + tid + 256] = f2b(o1);
}

// ---------------------------------------------------------------- chord gather (f32)
__global__ void gather_kernel(const float* __restrict__ h, const int* __restrict__ pos,
                              float* __restrict__ g) {
  int row = blockIdx.x;
  int b = row >> 7;
  int p = pos[row];
  if (p < 0) p = 0;
  size_t src = ((size_t)(b * TT + p)) * D_;
  size_t dst = (size_t)row * D_;
  for (int d = threadIdx.x; d < D_; d += 256) g[dst + d] = h[src + d];
}

// ---------------------------------------------------------------- launcher
extern "C" void kernel_launch(void* const* d_in, const int* in_sizes, int n_in,
                              void* d_out, int out_size, void* d_ws, size_t ws_size,
                              hipStream_t stream) {
  const int* x = (const int*)d_in[0];
  const int* cpos = (const int*)d_in[1];
  const float* emb = (const float*)d_in[2];
  const float* rel = (const float*)d_in[3];
  const float* Wq = (const float*)d_in[4];
  const float* bq = (const float*)d_in[5];
  const float* Wk = (const float*)d_in[6];
  const float* bk = (const float*)d_in[7];
  const float* Wv = (const float*)d_in[8];
  const float* bv = (const float*)d_in[9];
  const float* Wo = (const float*)d_in[10];
  const float* bo = (const float*)d_in[11];
  const float* ln1s = (const float*)d_in[12];
  const float* ln1b = (const float*)d_in[13];
  const float* W1 = (const float*)d_in[14];
  const float* b1 = (const float*)d_in[15];
  const float* W2 = (const float*)d_in[16];
  const float* b2 = (const float*)d_in[17];
  const float* ln2s = (const float*)d_in[18];
  const float* ln2b = (const float*)d_in[19];
  const float* Wout = (const float*)d_in[20];
  const float* bout = (const float*)d_in[21];
  const float* Wc = (const float*)d_in[22];
  const float* bc = (const float*)d_in[23];

  const size_t SZ = (size_t)BT_ * D_;
  const size_t WPROJ = (size_t)D_ * D_;
  const size_t WFFN = (size_t)D_ * F_;

  float* h = (float*)d_ws;
  float* y = h + SZ;
  ushort_t* h_bf = (ushort_t*)(y + SZ);
  ushort_t* qkv_bf = h_bf + SZ;
  ushort_t* o_bf = qkv_bf + (size_t)BT_ * 1536;
  ushort_t* mid_bf = o_bf + SZ;
  ushort_t* wqkvT = mid_bf + (size_t)BT_ * F_;
  ushort_t* woT = wqkvT + (size_t)L_ * 1536 * 512;
  ushort_t* w1T = woT + L_ * WPROJ;
  ushort_t* w2T = w1T + L_ * WFFN;
  ushort_t* woutT = w2T + L_ * WFFN;
  ushort_t* wcT = woutT + (size_t)D_ * V_;
  ushort_t* rel_bf = wcT + (size_t)D_ * C_;
  float* bqkv = (float*)(rel_bf + (size_t)L_ * NR_ * HD_);
  float* gath = bqkv + L_ * 1536;
  float* out = (float*)d_out;

  // ---- pre-pass (batched over layers)
  transpose_bf16_b<<<dim3(16, 16, 12), 256, 0, stream>>>(Wq, wqkvT, 512, 512, WPROJ, (size_t)1536 * 512);
  transpose_bf16_b<<<dim3(16, 16, 12), 256, 0, stream>>>(Wk, wqkvT + (size_t)512 * 512, 512, 512, WPROJ, (size_t)1536 * 512);
  transpose_bf16_b<<<dim3(16, 16, 12), 256, 0, stream>>>(Wv, wqkvT + (size_t)1024 * 512, 512, 512, WPROJ, (size_t)1536 * 512);
  transpose_bf16_b<<<dim3(16, 16, 12), 256, 0, stream>>>(Wo, woT, 512, 512, WPROJ, WPROJ);
  transpose_bf16_b<<<dim3(64, 16, 12), 256, 0, stream>>>(W1, w1T, 512, 2048, WFFN, WFFN);
  transpose_bf16_b<<<dim3(16, 64, 12), 256, 0, stream>>>(W2, w2T, 2048, 512, WFFN, WFFN);
  transpose_bf16_b<<<dim3(64, 16, 1), 256, 0, stream>>>(Wout, woutT, 512, 2048, 0, 0);
  transpose_bf16_b<<<dim3(2, 16, 1), 256, 0, stream>>>(Wc, wcT, 512, 64, 0, 0);
  rel_convert<<<1537, 256, 0, stream>>>(rel, rel_bf);
  pack_bias<<<(L_ * 1536 + 255) / 256, 256, 0, stream>>>(bq, bk, bv, bqkv);

  embed_kernel<<<BT_, 256, 0, stream>>>(x, emb, h, h_bf);

  dim3 gQKV(1536 / 128, BT_ / 128);
  dim3 gProj(D_ / 128, BT_ / 128);
  dim3 gF1(F_ / 128, BT_ / 128);
  dim3 gOut(V_ / 128, BT_ / 128);

  for (int l = 0; l < L_; ++l) {
    gemm_mfma<1, 0><<<gQKV, 256, 0, stream>>>(h_bf, wqkvT + (size_t)l * 1536 * 512,
                                              bqkv + l * 1536, qkv_bf, BT_, 1536, D_);
    attn_mfma<<<B_ * H_ * (TT / 64), 256, 0, stream>>>(qkv_bf, rel_bf + (size_t)l * NR_ * HD_, o_bf);
    gemm_mfma<0, 0><<<gProj, 256, 0, stream>>>(o_bf, woT + l * WPROJ, bo + l * D_, y, BT_, D_, D_);
    ln_res_kernel<<<BT_, 256, 0, stream>>>(h, y, ln1s + l * D_, ln1b + l * D_, h_bf);
    gemm_mfma<1, 1><<<gF1, 256, 0, stream>>>(h_bf, w1T + l * WFFN, b1 + l * F_, mid_bf, BT_, F_, D_);
    gemm_mfma<0, 0><<<gProj, 256, 0, stream>>>(mid_bf, w2T + l * WFFN, b2 + l * D_, y, BT_, D_, F_);
    ln_res_kernel<<<BT_, 256, 0, stream>>>(h, y, ln2s + l * D_, ln2b + l * D_, h_bf);
  }

  gemm_mfma<0, 0><<<gOut, 256, 0, stream>>>(h_bf, woutT, bout, out, BT_, V_, D_);
  gather_kernel<<<B_ * M_, 256, 0, stream>>>(h, cpos, gath);
  gemm_bias<0><<<dim3(1, (B_ * M_) / 64), 256, 0, stream>>>(gath, Wc, bc, out + (size_t)BT_ * V_,
                                                            B_ * M_, C_, D_);
}